// Round 13
// baseline (1209.312 us; speedup 1.0000x reference)
//
#include <hip/hip_runtime.h>
#include <hip/hip_bf16.h>
#include <math.h>

typedef __attribute__((ext_vector_type(8))) short s16x8;
typedef __attribute__((ext_vector_type(4))) float f32x4;

static __device__ __forceinline__ float bf2f(unsigned short u){
    unsigned int x = ((unsigned int)u) << 16; float f; __builtin_memcpy(&f,&x,4); return f;
}
static __device__ __forceinline__ unsigned short f2bf(float f){
    unsigned int x; __builtin_memcpy(&x,&f,4);
    unsigned int r = (x + 0x7FFFu + ((x>>16)&1u)) >> 16; return (unsigned short)r;
}

static __device__ __forceinline__ void stage16(const void* g, void* l){
    __builtin_amdgcn_global_load_lds((const __attribute__((address_space(1))) unsigned int*)g,
                                     (__attribute__((address_space(3))) unsigned int*)l, 16, 0, 0);
}

// ---------------- sizes ----------------
// N=64, C=128, T=128, V=25, S=3, K=7
// JN = 3200, NTV = 204800, PADROW = 3350, K-dim = 384*7 = 2688

// ---------------- setup: xt (0..6399) + wfold (6400..7295) + prep (7296..9343) ----------------
__global__ __launch_bounds__(256) void setup_kernel(const float* __restrict__ x,
                            const float* __restrict__ out_w, const float* __restrict__ ff_w,
                            const float* __restrict__ v_w,  const float* __restrict__ v_b,
                            const float* __restrict__ out_b, const float* __restrict__ out_g,
                            const float* __restrict__ out_be, const float* __restrict__ out_m,
                            const float* __restrict__ out_v,
                            const float* __restrict__ ff_b, const float* __restrict__ ff_g,
                            const float* __restrict__ ff_be, const float* __restrict__ ff_m,
                            const float* __restrict__ ff_v,
                            float* __restrict__ consts, unsigned short* __restrict__ ffA,
                            unsigned short* __restrict__ ypad, float* __restrict__ wbpart,
                            float* __restrict__ pebg, float* __restrict__ TPgb,
                            unsigned short* __restrict__ Wr,
                            unsigned short* __restrict__ xbt, unsigned short* __restrict__ xbu,
                            float* __restrict__ G, float* __restrict__ SX)
{
    __shared__ float tile[64][65];
    const int bid = blockIdx.x;
    const int tid = threadIdx.x;

    if (bid < 6400){
        int jb = bid % 50; int cb = (bid/50) & 1; int n = bid/100;
        int lane = tid & 63, wv = tid >> 6;
        size_t xbase = (size_t)n*409600;
        int jn = jb*64 + lane;
        int tt = jn/25, uu = jn - tt*25;
        size_t xbu_lb = (size_t)n*524288 + (size_t)tt*4096 + uu;
        #pragma unroll
        for (int r=wv; r<64; r+=4){
            float v = x[xbase + (size_t)(cb*64+r)*3200 + jb*64 + lane];
            tile[r][lane] = v;
            xbu[xbu_lb + (size_t)(cb*64+r)*32] = f2bf(v);
        }
        __syncthreads();
        #pragma unroll
        for (int j=wv; j<64; j+=4)
            xbt[xbase + (size_t)(jb*64+j)*128 + cb*64 + lane] = f2bf(tile[lane][j]);
        return;
    }

    if (bid < 7296){
        float* owl = &tile[0][0];
        int wb = bid - 6400;
        int o = wb/7, k = wb%7;
        for (int i=tid; i<384; i+=256) owl[i] = out_w[(size_t)(o*384 + i)*7 + k];
        __syncthreads();
        for (int sci=tid; sci<384; sci+=256){
            int s = sci >> 7, ci = sci & 127;
            const float* ow = owl + s*128;
            float acc = 0.f;
            #pragma unroll 8
            for (int c=0; c<128; ++c) acc += ow[c] * v_w[c*128 + ci];
            int kb = (sci>>5)*7 + k, jj = sci & 31;
            Wr[(size_t)o*2688 + kb*32 + jj] = f2bf(acc);
        }
        return;
    }

    // ---- prep ----
    const int stride = 2048*256;
    int i0 = (bid-7296)*256 + tid;
    const float KLN = 9.210340371976184f/128.f;   // ln(1e4)/C
    for (int i=i0; i<40000;  i+=stride) G[i]  = 0.f;
    for (int i=i0; i<204800; i+=stride) SX[i] = 0.f;
    for (int i=i0; i<16384; i+=stride) ffA[i] = f2bf(ff_w[i]);
    for (int i=i0; i<128; i+=stride){
        float inv  = out_g[i]/sqrtf(out_v[i]+1e-5f);
        consts[i]       = inv;
        consts[128+i]   = out_b[i]*inv + out_be[i] - out_m[i]*inv;
        float invf = ff_g[i]/sqrtf(ff_v[i]+1e-5f);
        consts[256+i]   = invf;
        consts[384+i]   = ff_b[i]*invf + ff_be[i] - ff_m[i]*invf;
    }
    for (int i=i0; i<3200; i+=stride){
        int v = i >> 7, c = i & 127;
        float freq = expf(-(float)(c & ~1) * KLN);
        float ang = (float)v * freq;
        pebg[i] = (c & 1) ? cosf(ang) : sinf(ang);
    }
    for (int i=i0; i<625; i+=stride){
        int u = i/25, v = i%25;
        float acc = 0.f;
        for (int c=0; c<128; ++c){
            float freq = expf(-(float)(c & ~1) * KLN);
            float pu = (c & 1) ? cosf((float)u*freq) : sinf((float)u*freq);
            float pv = (c & 1) ? cosf((float)v*freq) : sinf((float)v*freq);
            acc += pu*pv;
        }
        TPgb[i] = 128.f*acc;
    }
    for (int i=i0; i<2688; i+=stride){
        int o = i/21, rem = i%21, s = rem/7, tc = rem%7;
        int kmin = (tc<3) ? (3-tc) : 0;
        int kmax = (tc>3) ? (10-tc) : 7;
        float acc = 0.f;
        for (int c=0; c<128; ++c){
            const float* wp = out_w + (size_t)(o*384 + s*128 + c)*7;
            float vb = v_b[c];
            for (int k=kmin; k<kmax; ++k) acc += wp[k]*vb;
        }
        wbpart[i] = acc;
    }
    // zero the temporal halo pads of Ypad
    for (int i=i0; i<3686400; i+=stride){
        int n2 = i/57600, r2 = i%57600;
        int pp = r2/384, sc = r2%384;
        int ppos = (pp < 75) ? pp : (3200 + pp);
        ypad[(size_t)(n2*3350 + ppos)*384 + sc] = 0;
    }
    // NOTE: xbu u-pads (u=25..31) left as garbage; agg_mfma masks them in-register.
}

// ---------------- gram part: partial Gx (MFMA) + partial sx, atomics, 512 blocks ----------------
__global__ __launch_bounds__(256) void gram_part(const unsigned short* __restrict__ xbt,
                                                 float* __restrict__ G, float* __restrict__ SX){
    __shared__ float glx[4][32][32];
    int bid = blockIdx.x; int n = bid >> 3; int chunk = bid & 7;
    int tid = threadIdx.x;
    const unsigned short* xb = xbt + (size_t)n*409600;

    int c = tid & 127, th = tid >> 7;
    float a[25];
    #pragma unroll
    for (int u=0; u<25; ++u) a[u] = 0.f;
    for (int tt=0; tt<8; ++tt){
        int t = chunk*16 + th*8 + tt;
        const unsigned short* row = xb + (size_t)t*3200 + c;
        #pragma unroll
        for (int u=0; u<25; ++u) a[u] += bf2f(row[u*128]);
    }
    float* tmp = &glx[0][0][0];
    if (th){
        #pragma unroll
        for (int u=0; u<25; ++u) tmp[u*128+c] = a[u];
    }
    __syncthreads();
    if (!th){
        #pragma unroll
        for (int u=0; u<25; ++u) atomicAdd(&SX[n*3200 + u*128 + c], a[u] + tmp[u*128+c]);
    }
    __syncthreads();

    int lane = tid & 63, w = tid >> 6;
    int lr = lane & 15, lg = lane >> 4;
    f32x4 acc[2][2];
    #pragma unroll
    for (int i2=0;i2<2;i2++)
        #pragma unroll
        for (int j2=0;j2<2;j2++) acc[i2][j2] = (f32x4){0.f,0.f,0.f,0.f};
    for (int tt=0; tt<4; ++tt){
        int t = chunk*16 + w*4 + tt;
        const unsigned short* tb = xb + (size_t)t*3200;
        #pragma unroll
        for (int kc=0; kc<4; ++kc){
            s16x8 f0 = *(const s16x8*)(tb + (size_t)(lr)*128    + kc*32 + lg*8);
            s16x8 f1 = *(const s16x8*)(tb + (size_t)(16+lr)*128 + kc*32 + lg*8);
            acc[0][0] = __builtin_amdgcn_mfma_f32_16x16x32_bf16(f0, f0, acc[0][0], 0,0,0);
            acc[0][1] = __builtin_amdgcn_mfma_f32_16x16x32_bf16(f0, f1, acc[0][1], 0,0,0);
            acc[1][0] = __builtin_amdgcn_mfma_f32_16x16x32_bf16(f1, f0, acc[1][0], 0,0,0);
            acc[1][1] = __builtin_amdgcn_mfma_f32_16x16x32_bf16(f1, f1, acc[1][1], 0,0,0);
        }
    }
    #pragma unroll
    for (int mh=0; mh<2; ++mh)
        #pragma unroll
        for (int nh=0; nh<2; ++nh)
            #pragma unroll
            for (int r=0; r<4; ++r)
                glx[w][mh*16 + lg*4 + r][nh*16 + lr] = acc[mh][nh][r];
    __syncthreads();
    for (int idx=tid; idx<625; idx+=256){
        int u = idx/25, v = idx%25;
        atomicAdd(&G[n*625 + idx], glx[0][u][v] + glx[1][u][v] + glx[2][u][v] + glx[3][u][v]);
    }
}

// ---------------- gram fin: G += pe correction; also per-n d2 max ----------------
__global__ __launch_bounds__(256) void gram_fin(const float* __restrict__ SX,
                                                const float* __restrict__ pebg,
                                                const float* __restrict__ TPgb,
                                                float* __restrict__ G,
                                                float* __restrict__ nmax){
    __shared__ float sxl[25][129];
    __shared__ float pebl[25][129];
    __shared__ float gf[625];
    __shared__ float red[256];
    int n = blockIdx.x, tid = threadIdx.x;
    for (int i=tid; i<3200; i+=256){
        sxl[i>>7][i&127]  = SX[n*3200 + i];
        pebl[i>>7][i&127] = pebg[i];
    }
    __syncthreads();
    for (int idx=tid; idx<625; idx+=256){
        int u = idx/25, v = idx%25;
        float cr = TPgb[idx];
        #pragma unroll 4
        for (int cc=0; cc<128; ++cc)
            cr += sxl[u][cc]*pebl[v][cc] + sxl[v][cc]*pebl[u][cc];
        float val = G[n*625 + idx] + cr;
        G[n*625 + idx] = val;
        gf[idx] = val;
    }
    __syncthreads();
    float mx = 0.f;
    for (int idx=tid; idx<625; idx+=256){
        int u = idx/25, v = idx%25;
        float d2 = fmaxf(gf[u*26] + gf[v*26] - 2.f*gf[u*25+v], 0.f);
        mx = fmaxf(mx, d2);
    }
    red[tid] = mx; __syncthreads();
    for (int s2=128; s2>0; s2>>=1){ if (tid < s2) red[tid] = fmaxf(red[tid], red[tid+s2]); __syncthreads(); }
    if (tid == 0) nmax[n] = red[0];
}

// ---------------- attention: 64 blocks (one per n) ----------------
__global__ __launch_bounds__(128) void attn_kernel(const float* __restrict__ G, const float* __restrict__ nmax,
                                                   const float* __restrict__ theta,
                                                   const float* __restrict__ atts, const float* __restrict__ alphas,
                                                   unsigned short* __restrict__ att_pad, float* __restrict__ asum){
    __shared__ float gl[625];
    __shared__ float red[64];
    int n = blockIdx.x, tid = threadIdx.x;
    if (tid < 64) red[tid] = nmax[tid];
    for (int i=tid; i<625; i+=128) gl[i] = G[n*625 + i];
    __syncthreads();
    if (tid == 0){
        float m = red[0];
        for (int i=1; i<64; ++i) m = fmaxf(m, red[i]);
        red[0] = m;
    }
    __syncthreads();
    float inv = 1.f/red[0];
    for (int i=tid; i<160; i+=128) att_pad[n*2560 + 2400 + i] = 0;
    if (tid < 75){
        int s = tid/25, vc = tid%25;
        float et = expf(theta[s]);
        float al = alphas[s];
        float gvv = gl[vc*26];
        float z[25];
        #pragma unroll
        for (int u2=0; u2<25; ++u2){
            float d2v = fmaxf(gl[u2*26] + gvv - 2.f*gl[u2*25+vc], 0.f);
            z[u2] = expf(-et*d2v*inv);
        }
        float zm = z[0];
        #pragma unroll
        for (int u2=1; u2<25; ++u2) zm = fmaxf(zm, z[u2]);
        float lo = zm - 1.f, hi = zm;
        for (int it=0; it<30; ++it){
            float mid = 0.5f*(lo+hi);
            float f = 0.f;
            #pragma unroll
            for (int u2=0; u2<25; ++u2) f += fmaxf(z[u2]-mid, 0.f);
            if (f >= 1.f) lo = mid; else hi = mid;
        }
        float ssum = 0.f; int kcnt = 0;
        #pragma unroll
        for (int u2=0; u2<25; ++u2){ if (z[u2] > lo){ ssum += z[u2]; kcnt++; } }
        float tau = (ssum - 1.f)/(float)kcnt;
        float as_ = 0.f;
        unsigned short* apr = att_pad + n*2560 + (s*25+vc)*32;
        #pragma unroll
        for (int u2=0; u2<25; ++u2){
            float av = atts[s*625 + u2*25 + vc] + fmaxf(z[u2]-tau, 0.f)*al;
            apr[u2] = f2bf(av);
            as_ += av;
        }
        #pragma unroll
        for (int u2=25; u2<32; ++u2) apr[u2] = 0;
        asum[n*75 + s*25 + vc] = as_;
    }
}

// ---------------- agg via MFMA (xbu u-pads masked in-register) ----------------
__global__ __launch_bounds__(256,2) void agg_mfma(const unsigned short* __restrict__ att_pad,
                                                  const unsigned short* __restrict__ xbu,
                                                  unsigned short* __restrict__ ypad){
    int bid = blockIdx.x; int n = bid >> 4; int tb = bid & 15;
    int tid = threadIdx.x; int lane = tid & 63; int w = tid >> 6;
    int lr = lane & 15, lg = lane >> 4;
    const unsigned short* ap = att_pad + n*2560;
    s16x8 a[5];
    #pragma unroll
    for (int mf=0; mf<5; ++mf) a[mf] = *(const s16x8*)&ap[(mf*16+lr)*32 + lg*8];
    int rowoff[5][4];
    #pragma unroll
    for (int mf=0; mf<5; ++mf)
        #pragma unroll
        for (int r=0; r<4; ++r){
            int m = mf*16 + lg*4 + r;
            int s = m/25, v = m - s*25;
            rowoff[mf][r] = (m < 75) ? (v*384 + s*128 + lr) : -1;
        }
    #pragma unroll
    for (int ti=0; ti<2; ++ti){
        int t = tb*8 + w*2 + ti;
        const unsigned short* bp = xbu + (size_t)n*524288 + (size_t)t*4096;
        size_t obase = ((size_t)(n*3350 + 75 + t*25))*384;
        #pragma unroll
        for (int h=0; h<2; ++h){
            s16x8 b[4];
            #pragma unroll
            for (int q=0; q<4; ++q){
                b[q] = *(const s16x8*)&bp[(h*64 + q*16 + lr)*32 + lg*8];
                if (lg == 3){
                    s16x8 t2 = b[q];
                    b[q] = (s16x8){t2[0],0,0,0,0,0,0,0};
                }
            }
            f32x4 acc[5][4];
            #pragma unroll
            for (int mf=0; mf<5; ++mf)
                #pragma unroll
                for (int q=0; q<4; ++q)
                    acc[mf][q] = (f32x4){0.f,0.f,0.f,0.f};
            #pragma unroll
            for (int mf=0; mf<5; ++mf)
                #pragma unroll
                for (int q=0; q<4; ++q)
                    acc[mf][q] = __builtin_amdgcn_mfma_f32_16x16x32_bf16(a[mf], b[q], acc[mf][q], 0, 0, 0);
            #pragma unroll
            for (int mf=0; mf<5; ++mf)
                #pragma unroll
                for (int q=0; q<4; ++q)
                    #pragma unroll
                    for (int r=0; r<4; ++r)
                        if (rowoff[mf][r] >= 0)
                            ypad[obase + rowoff[mf][r] + h*64 + q*16] = f2bf(acc[mf][q][r]);
        }
    }
}

// ---------------- fused conv+ff GEMM v7: BK=64, 32 KB LDS (5 blocks/CU), 2-phase epilogue ----------------
__global__ __launch_bounds__(256,3) void gemm_fused(const unsigned short* __restrict__ Amat,
                                                    const unsigned short* __restrict__ Bsrc,
                                                    const float* __restrict__ xin,
                                                    const float* __restrict__ consts,
                                                    const unsigned short* __restrict__ ffA,
                                                    const float* __restrict__ wbpart,
                                                    const float* __restrict__ asum,
                                                    float* __restrict__ outf)
{
    constexpr int NKB = 42;                   // 42 K-steps of BK=64
    __shared__ unsigned short smem[16384];    // exactly 32 KB: loop A(16KB)+B(16KB); epilogue 64x136 tile (17.4KB)

    const int tid = threadIdx.x;
    const int bid = blockIdx.x;
    const int n   = bid/25;
    const int jn0 = (bid%25)*128;

    const int lane = tid & 63, wv = tid >> 6;
    const int wm = wv >> 1, wn = wv & 1;
    const int lr = lane & 15, lg = lane >> 4;
    const int swz = (lg ^ (lr&3)) << 3;       // read swizzle within each 32-short half

    unsigned short* sA = smem;
    unsigned short* sB = smem + 8192;

    auto stage = [&](int kb){
        #pragma unroll
        for (int p=0; p<4; ++p){
            int e = p*256 + tid;
            int r = e >> 3, cch = e & 7;
            int half = cch >> 2, cc = (cch&3) ^ (r&3);
            stage16(Amat + (size_t)r*2688 + kb*64 + half*32 + cc*8, sA + e*8);
        }
        int k32a = 2*kb, k32b = 2*kb + 1;
        int k0 = k32a % 7, s0 = (k32a/7)*32;
        int k1 = k32b % 7, s1 = (k32b/7)*32;
        const unsigned short* b0 = Bsrc + ((size_t)(n*3350 + jn0 + 25*k0))*384 + s0;
        const unsigned short* b1 = Bsrc + ((size_t)(n*3350 + jn0 + 25*k1))*384 + s1;
        #pragma unroll
        for (int p=0; p<4; ++p){
            int e = p*256 + tid;
            int r = e >> 3, cch = e & 7;
            int half = cch >> 2, cc = (cch&3) ^ (r&3);
            const unsigned short* src = (half ? b1 : b0) + (size_t)r*384 + cc*8;
            stage16(src, sB + e*8);
        }
    };

    f32x4 acc[4][4];
    #pragma unroll
    for (int a2=0;a2<4;a2++)
        #pragma unroll
        for (int b2=0;b2<4;b2++) acc[a2][b2] = (f32x4){0.f,0.f,0.f,0.f};

    for (int kb=0; kb<NKB; ++kb){
        stage(kb);
        __syncthreads();
        s16x8 a[4][2], b[4][2];
        #pragma unroll
        for (int mf=0; mf<4; ++mf)
            #pragma unroll
            for (int kf=0; kf<2; ++kf)
                a[mf][kf] = *(const s16x8*)&sA[(wm*64+mf*16+lr)*64 + kf*32 + swz];
        #pragma unroll
        for (int nf=0; nf<4; ++nf)
            #pragma unroll
            for (int kf=0; kf<2; ++kf)
                b[nf][kf] = *(const s16x8*)&sB[(wn*64+nf*16+lr)*64 + kf*32 + swz];
        __builtin_amdgcn_s_setprio(1);
        #pragma unroll
        for (int kf=0; kf<2; ++kf)
            #pragma unroll
            for (int mf=0; mf<4; ++mf)
                #pragma unroll
                for (int nf=0; nf<4; ++nf)
                    acc[mf][nf] = __builtin_amdgcn_mfma_f32_16x16x32_bf16(a[mf][kf], b[nf][kf], acc[mf][nf], 0, 0, 0);
        __builtin_amdgcn_s_setprio(0);
        __syncthreads();
    }

    // ---------- 2-phase epilogue: 64 cols at a time through a 64x136 tile ----------
    const float* asn = asum + n*75;
    for (int ph=0; ph<2; ++ph){
        if (wn == ph){
            #pragma unroll
            for (int nf=0; nf<4; ++nf){
                int cj = wn*64 + nf*16 + lr;
                int j  = jn0 + cj;
                int t  = j/25, v = j - t*25;
                int tc = (t<3) ? t : ((t>124) ? (t-121) : 3);
                float a0 = asn[v], a1 = asn[25+v], a2 = asn[50+v];
                #pragma unroll
                for (int mf=0; mf<4; ++mf)
                    #pragma unroll
                    for (int r=0; r<4; ++r){
                        int m = wm*64 + mf*16 + lg*4 + r;
                        float b2v = wbpart[m*21+tc]*a0 + wbpart[m*21+7+tc]*a1 + wbpart[m*21+14+tc]*a2;
                        float val = acc[mf][nf][r]*consts[m] + consts[128+m] + b2v
                                  + xin[(size_t)n*409600 + (size_t)m*3200 + j];
                        val = (val >= 0.f) ? val : 0.1f*val;
                        smem[(cj - ph*64)*136 + m] = f2bf(val);
                    }
            }
        }
        __syncthreads();

        // ff GEMM on these 64 cols: M=128, N=64, K=128; 4 waves, wave tile 64x32
        f32x4 acc2[4][2];
        #pragma unroll
        for (int a2=0;a2<4;a2++)
            #pragma unroll
            for (int b2=0;b2<2;b2++) acc2[a2][b2] = (f32x4){0.f,0.f,0.f,0.f};
        #pragma unroll
        for (int kb2=0; kb2<4; ++kb2){
            s16x8 a2[4], b2[2];
            #pragma unroll
            for (int mf=0; mf<4; ++mf)
                a2[mf] = *(const s16x8*)&ffA[(size_t)(wm*64+mf*16+lr)*128 + kb2*32 + lg*8];
            #pragma unroll
            for (int nf2=0; nf2<2; ++nf2)
                b2[nf2] = *(const s16x8*)&smem[(wn*32+nf2*16+lr)*136 + kb2*32 + lg*8];
            #pragma unroll
            for (int mf=0; mf<4; ++mf)
                #pragma unroll
                for (int nf2=0; nf2<2; ++nf2)
                    acc2[mf][nf2] = __builtin_amdgcn_mfma_f32_16x16x32_bf16(a2[mf], b2[nf2], acc2[mf][nf2], 0, 0, 0);
        }

        #pragma unroll
        for (int mf=0; mf<4; ++mf)
            #pragma unroll
            for (int r=0; r<4; ++r){
                int co = wm*64 + mf*16 + lg*4 + r;
                float sc2 = consts[256+co], bi2 = consts[384+co];
                #pragma unroll
                for (int nf2=0; nf2<2; ++nf2){
                    int cj = ph*64 + wn*32 + nf2*16 + lr;
                    size_t idx = (size_t)n*409600 + (size_t)co*3200 + jn0 + cj;
                    float val = acc2[mf][nf2][r]*sc2 + bi2 + xin[idx];
                    val = (val >= 0.f) ? val : 0.1f*val;
                    outf[idx] = val;
                }
            }
        __syncthreads();   // tile region free before next phase's stores
    }
}

extern "C" void kernel_launch(void* const* d_in, const int* in_sizes, int n_in,
                              void* d_out, int out_size, void* d_ws, size_t ws_size,
                              hipStream_t stream) {
    const float* x      = (const float*)d_in[0];
    const float* theta  = (const float*)d_in[1];
    const float* atts   = (const float*)d_in[2];
    const float* alphas = (const float*)d_in[3];
    const float* v_w    = (const float*)d_in[4];
    const float* v_b    = (const float*)d_in[5];
    const float* out_w  = (const float*)d_in[6];
    const float* out_b  = (const float*)d_in[7];
    const float* out_g  = (const float*)d_in[8];
    const float* out_be = (const float*)d_in[9];
    const float* out_m  = (const float*)d_in[10];
    const float* out_v  = (const float*)d_in[11];
    const float* ff_w   = (const float*)d_in[12];
    const float* ff_b   = (const float*)d_in[13];
    const float* ff_g   = (const float*)d_in[14];
    const float* ff_be  = (const float*)d_in[15];
    const float* ff_m   = (const float*)d_in[16];
    const float* ff_v   = (const float*)d_in[17];
    float* out = (float*)d_out;

    char* w = (char*)d_ws;
    size_t off = 0;
    auto alloc = [&](size_t b){ size_t r = off; off += (b + 1023) & ~(size_t)1023; return r; };
    float*          G      = (float*)         (w + alloc(160000));
    float*          SX     = (float*)         (w + alloc(819200));
    float*          nmaxb  = (float*)         (w + alloc(256));
    float*          asumb  = (float*)         (w + alloc(19200));
    float*          consts = (float*)         (w + alloc(2048));
    float*          wbpart = (float*)         (w + alloc(10752));
    float*          pebg   = (float*)         (w + alloc(12800));
    float*          TPgb   = (float*)         (w + alloc(2500));
    unsigned short* att_pad= (unsigned short*)(w + alloc(327680));
    unsigned short* Wr     = (unsigned short*)(w + alloc(688128));
    unsigned short* ffA    = (unsigned short*)(w + alloc(32768));
    unsigned short* xbt    = (unsigned short*)(w + alloc(52428800 + 16384));
    unsigned short* xbu    = (unsigned short*)(w + alloc(67108864));
    unsigned short* ypad   = (unsigned short*)(w + alloc(164659200));

    setup_kernel<<<9344,256,0,stream>>>(x, out_w, ff_w, v_w, v_b, out_b, out_g, out_be, out_m, out_v,
                                        ff_b, ff_g, ff_be, ff_m, ff_v,
                                        consts, ffA, ypad, wbpart, pebg, TPgb, Wr, xbt, xbu, G, SX);
    gram_part<<<512,256,0,stream>>>(xbt, G, SX);
    gram_fin<<<64,256,0,stream>>>(SX, pebg, TPgb, G, nmaxb);
    attn_kernel<<<64,128,0,stream>>>(G, nmaxb, theta, atts, alphas, att_pad, asumb);
    agg_mfma<<<1024,256,0,stream>>>(att_pad, xbu, ypad);
    gemm_fused<<<1600,256,0,stream>>>(Wr, ypad, x, consts, ffA, wbpart, asumb, out);
}

// Round 14
// 646.807 us; speedup vs baseline: 1.8697x; 1.8697x over previous
//
#include <hip/hip_runtime.h>
#include <hip/hip_bf16.h>
#include <math.h>

typedef __attribute__((ext_vector_type(8))) short s16x8;
typedef __attribute__((ext_vector_type(4))) float f32x4;

static __device__ __forceinline__ float bf2f(unsigned short u){
    unsigned int x = ((unsigned int)u) << 16; float f; __builtin_memcpy(&f,&x,4); return f;
}
static __device__ __forceinline__ unsigned short f2bf(float f){
    unsigned int x; __builtin_memcpy(&x,&f,4);
    unsigned int r = (x + 0x7FFFu + ((x>>16)&1u)) >> 16; return (unsigned short)r;
}

static __device__ __forceinline__ void stage16(const void* g, void* l){
    __builtin_amdgcn_global_load_lds((const __attribute__((address_space(1))) unsigned int*)g,
                                     (__attribute__((address_space(3))) unsigned int*)l, 16, 0, 0);
}

// ---------------- sizes ----------------
// N=64, C=128, T=128, V=25, S=3, K=7
// JN = 3200, NTV = 204800, PADROW = 3350, K-dim = 384*7 = 2688

// ---------------- setup: xt (0..6399) + wfold (6400..7295) + prep (7296..9343) ----------------
__global__ __launch_bounds__(256) void setup_kernel(const float* __restrict__ x,
                            const float* __restrict__ out_w, const float* __restrict__ ff_w,
                            const float* __restrict__ v_w,  const float* __restrict__ v_b,
                            const float* __restrict__ out_b, const float* __restrict__ out_g,
                            const float* __restrict__ out_be, const float* __restrict__ out_m,
                            const float* __restrict__ out_v,
                            const float* __restrict__ ff_b, const float* __restrict__ ff_g,
                            const float* __restrict__ ff_be, const float* __restrict__ ff_m,
                            const float* __restrict__ ff_v,
                            float* __restrict__ consts, unsigned short* __restrict__ ffA,
                            unsigned short* __restrict__ ypad, float* __restrict__ wbpart,
                            float* __restrict__ pebg, float* __restrict__ TPgb,
                            unsigned short* __restrict__ Wr,
                            unsigned short* __restrict__ xbt, unsigned short* __restrict__ xbu,
                            float* __restrict__ G, float* __restrict__ SX)
{
    __shared__ float tile[64][65];
    const int bid = blockIdx.x;
    const int tid = threadIdx.x;

    if (bid < 6400){
        int jb = bid % 50; int cb = (bid/50) & 1; int n = bid/100;
        int lane = tid & 63, wv = tid >> 6;
        size_t xbase = (size_t)n*409600;
        int jn = jb*64 + lane;
        int tt = jn/25, uu = jn - tt*25;
        size_t xbu_lb = (size_t)n*524288 + (size_t)tt*4096 + uu;
        #pragma unroll
        for (int r=wv; r<64; r+=4){
            float v = x[xbase + (size_t)(cb*64+r)*3200 + jb*64 + lane];
            tile[r][lane] = v;
            xbu[xbu_lb + (size_t)(cb*64+r)*32] = f2bf(v);
        }
        __syncthreads();
        #pragma unroll
        for (int j=wv; j<64; j+=4)
            xbt[xbase + (size_t)(jb*64+j)*128 + cb*64 + lane] = f2bf(tile[lane][j]);
        return;
    }

    if (bid < 7296){
        float* owl = &tile[0][0];
        int wb = bid - 6400;
        int o = wb/7, k = wb%7;
        for (int i=tid; i<384; i+=256) owl[i] = out_w[(size_t)(o*384 + i)*7 + k];
        __syncthreads();
        for (int sci=tid; sci<384; sci+=256){
            int s = sci >> 7, ci = sci & 127;
            const float* ow = owl + s*128;
            float acc = 0.f;
            #pragma unroll 8
            for (int c=0; c<128; ++c) acc += ow[c] * v_w[c*128 + ci];
            int kb = (sci>>5)*7 + k, jj = sci & 31;
            Wr[(size_t)o*2688 + kb*32 + jj] = f2bf(acc);
        }
        return;
    }

    // ---- prep ----
    const int stride = 2048*256;
    int i0 = (bid-7296)*256 + tid;
    const float KLN = 9.210340371976184f/128.f;   // ln(1e4)/C
    for (int i=i0; i<40000;  i+=stride) G[i]  = 0.f;
    for (int i=i0; i<204800; i+=stride) SX[i] = 0.f;
    for (int i=i0; i<16384; i+=stride) ffA[i] = f2bf(ff_w[i]);
    for (int i=i0; i<128; i+=stride){
        float inv  = out_g[i]/sqrtf(out_v[i]+1e-5f);
        consts[i]       = inv;
        consts[128+i]   = out_b[i]*inv + out_be[i] - out_m[i]*inv;
        float invf = ff_g[i]/sqrtf(ff_v[i]+1e-5f);
        consts[256+i]   = invf;
        consts[384+i]   = ff_b[i]*invf + ff_be[i] - ff_m[i]*invf;
    }
    for (int i=i0; i<3200; i+=stride){
        int v = i >> 7, c = i & 127;
        float freq = expf(-(float)(c & ~1) * KLN);
        float ang = (float)v * freq;
        pebg[i] = (c & 1) ? cosf(ang) : sinf(ang);
    }
    for (int i=i0; i<625; i+=stride){
        int u = i/25, v = i%25;
        float acc = 0.f;
        for (int c=0; c<128; ++c){
            float freq = expf(-(float)(c & ~1) * KLN);
            float pu = (c & 1) ? cosf((float)u*freq) : sinf((float)u*freq);
            float pv = (c & 1) ? cosf((float)v*freq) : sinf((float)v*freq);
            acc += pu*pv;
        }
        TPgb[i] = 128.f*acc;
    }
    for (int i=i0; i<2688; i+=stride){
        int o = i/21, rem = i%21, s = rem/7, tc = rem%7;
        int kmin = (tc<3) ? (3-tc) : 0;
        int kmax = (tc>3) ? (10-tc) : 7;
        float acc = 0.f;
        for (int c=0; c<128; ++c){
            const float* wp = out_w + (size_t)(o*384 + s*128 + c)*7;
            float vb = v_b[c];
            for (int k=kmin; k<kmax; ++k) acc += wp[k]*vb;
        }
        wbpart[i] = acc;
    }
    // zero the temporal halo pads of Ypad
    for (int i=i0; i<3686400; i+=stride){
        int n2 = i/57600, r2 = i%57600;
        int pp = r2/384, sc = r2%384;
        int ppos = (pp < 75) ? pp : (3200 + pp);
        ypad[(size_t)(n2*3350 + ppos)*384 + sc] = 0;
    }
    // NOTE: xbu u-pads (u=25..31) left as garbage; agg_mfma masks them in-register.
}

// ---------------- gram part: partial Gx (MFMA) + partial sx, atomics, 512 blocks ----------------
__global__ __launch_bounds__(256) void gram_part(const unsigned short* __restrict__ xbt,
                                                 float* __restrict__ G, float* __restrict__ SX){
    __shared__ float glx[4][32][32];
    int bid = blockIdx.x; int n = bid >> 3; int chunk = bid & 7;
    int tid = threadIdx.x;
    const unsigned short* xb = xbt + (size_t)n*409600;

    int c = tid & 127, th = tid >> 7;
    float a[25];
    #pragma unroll
    for (int u=0; u<25; ++u) a[u] = 0.f;
    for (int tt=0; tt<8; ++tt){
        int t = chunk*16 + th*8 + tt;
        const unsigned short* row = xb + (size_t)t*3200 + c;
        #pragma unroll
        for (int u=0; u<25; ++u) a[u] += bf2f(row[u*128]);
    }
    float* tmp = &glx[0][0][0];
    if (th){
        #pragma unroll
        for (int u=0; u<25; ++u) tmp[u*128+c] = a[u];
    }
    __syncthreads();
    if (!th){
        #pragma unroll
        for (int u=0; u<25; ++u) atomicAdd(&SX[n*3200 + u*128 + c], a[u] + tmp[u*128+c]);
    }
    __syncthreads();

    int lane = tid & 63, w = tid >> 6;
    int lr = lane & 15, lg = lane >> 4;
    f32x4 acc[2][2];
    #pragma unroll
    for (int i2=0;i2<2;i2++)
        #pragma unroll
        for (int j2=0;j2<2;j2++) acc[i2][j2] = (f32x4){0.f,0.f,0.f,0.f};
    for (int tt=0; tt<4; ++tt){
        int t = chunk*16 + w*4 + tt;
        const unsigned short* tb = xb + (size_t)t*3200;
        #pragma unroll
        for (int kc=0; kc<4; ++kc){
            s16x8 f0 = *(const s16x8*)(tb + (size_t)(lr)*128    + kc*32 + lg*8);
            s16x8 f1 = *(const s16x8*)(tb + (size_t)(16+lr)*128 + kc*32 + lg*8);
            acc[0][0] = __builtin_amdgcn_mfma_f32_16x16x32_bf16(f0, f0, acc[0][0], 0,0,0);
            acc[0][1] = __builtin_amdgcn_mfma_f32_16x16x32_bf16(f0, f1, acc[0][1], 0,0,0);
            acc[1][0] = __builtin_amdgcn_mfma_f32_16x16x32_bf16(f1, f0, acc[1][0], 0,0,0);
            acc[1][1] = __builtin_amdgcn_mfma_f32_16x16x32_bf16(f1, f1, acc[1][1], 0,0,0);
        }
    }
    #pragma unroll
    for (int mh=0; mh<2; ++mh)
        #pragma unroll
        for (int nh=0; nh<2; ++nh)
            #pragma unroll
            for (int r=0; r<4; ++r)
                glx[w][mh*16 + lg*4 + r][nh*16 + lr] = acc[mh][nh][r];
    __syncthreads();
    for (int idx=tid; idx<625; idx+=256){
        int u = idx/25, v = idx%25;
        atomicAdd(&G[n*625 + idx], glx[0][u][v] + glx[1][u][v] + glx[2][u][v] + glx[3][u][v]);
    }
}

// ---------------- gram fin: G += pe correction; also per-n d2 max ----------------
__global__ __launch_bounds__(256) void gram_fin(const float* __restrict__ SX,
                                                const float* __restrict__ pebg,
                                                const float* __restrict__ TPgb,
                                                float* __restrict__ G,
                                                float* __restrict__ nmax){
    __shared__ float sxl[25][129];
    __shared__ float pebl[25][129];
    __shared__ float gf[625];
    __shared__ float red[256];
    int n = blockIdx.x, tid = threadIdx.x;
    for (int i=tid; i<3200; i+=256){
        sxl[i>>7][i&127]  = SX[n*3200 + i];
        pebl[i>>7][i&127] = pebg[i];
    }
    __syncthreads();
    for (int idx=tid; idx<625; idx+=256){
        int u = idx/25, v = idx%25;
        float cr = TPgb[idx];
        #pragma unroll 4
        for (int cc=0; cc<128; ++cc)
            cr += sxl[u][cc]*pebl[v][cc] + sxl[v][cc]*pebl[u][cc];
        float val = G[n*625 + idx] + cr;
        G[n*625 + idx] = val;
        gf[idx] = val;
    }
    __syncthreads();
    float mx = 0.f;
    for (int idx=tid; idx<625; idx+=256){
        int u = idx/25, v = idx%25;
        float d2 = fmaxf(gf[u*26] + gf[v*26] - 2.f*gf[u*25+v], 0.f);
        mx = fmaxf(mx, d2);
    }
    red[tid] = mx; __syncthreads();
    for (int s2=128; s2>0; s2>>=1){ if (tid < s2) red[tid] = fmaxf(red[tid], red[tid+s2]); __syncthreads(); }
    if (tid == 0) nmax[n] = red[0];
}

// ---------------- attention: 64 blocks (one per n) ----------------
__global__ __launch_bounds__(128) void attn_kernel(const float* __restrict__ G, const float* __restrict__ nmax,
                                                   const float* __restrict__ theta,
                                                   const float* __restrict__ atts, const float* __restrict__ alphas,
                                                   unsigned short* __restrict__ att_pad, float* __restrict__ asum){
    __shared__ float gl[625];
    __shared__ float red[64];
    int n = blockIdx.x, tid = threadIdx.x;
    if (tid < 64) red[tid] = nmax[tid];
    for (int i=tid; i<625; i+=128) gl[i] = G[n*625 + i];
    __syncthreads();
    if (tid == 0){
        float m = red[0];
        for (int i=1; i<64; ++i) m = fmaxf(m, red[i]);
        red[0] = m;
    }
    __syncthreads();
    float inv = 1.f/red[0];
    for (int i=tid; i<160; i+=128) att_pad[n*2560 + 2400 + i] = 0;
    if (tid < 75){
        int s = tid/25, vc = tid%25;
        float et = expf(theta[s]);
        float al = alphas[s];
        float gvv = gl[vc*26];
        float z[25];
        #pragma unroll
        for (int u2=0; u2<25; ++u2){
            float d2v = fmaxf(gl[u2*26] + gvv - 2.f*gl[u2*25+vc], 0.f);
            z[u2] = expf(-et*d2v*inv);
        }
        float zm = z[0];
        #pragma unroll
        for (int u2=1; u2<25; ++u2) zm = fmaxf(zm, z[u2]);
        float lo = zm - 1.f, hi = zm;
        for (int it=0; it<30; ++it){
            float mid = 0.5f*(lo+hi);
            float f = 0.f;
            #pragma unroll
            for (int u2=0; u2<25; ++u2) f += fmaxf(z[u2]-mid, 0.f);
            if (f >= 1.f) lo = mid; else hi = mid;
        }
        float ssum = 0.f; int kcnt = 0;
        #pragma unroll
        for (int u2=0; u2<25; ++u2){ if (z[u2] > lo){ ssum += z[u2]; kcnt++; } }
        float tau = (ssum - 1.f)/(float)kcnt;
        float as_ = 0.f;
        unsigned short* apr = att_pad + n*2560 + (s*25+vc)*32;
        #pragma unroll
        for (int u2=0; u2<25; ++u2){
            float av = atts[s*625 + u2*25 + vc] + fmaxf(z[u2]-tau, 0.f)*al;
            apr[u2] = f2bf(av);
            as_ += av;
        }
        #pragma unroll
        for (int u2=25; u2<32; ++u2) apr[u2] = 0;
        asum[n*75 + s*25 + vc] = as_;
    }
}

// ---------------- agg via MFMA (xbu u-pads masked in-register) ----------------
__global__ __launch_bounds__(256,2) void agg_mfma(const unsigned short* __restrict__ att_pad,
                                                  const unsigned short* __restrict__ xbu,
                                                  unsigned short* __restrict__ ypad){
    int bid = blockIdx.x; int n = bid >> 4; int tb = bid & 15;
    int tid = threadIdx.x; int lane = tid & 63; int w = tid >> 6;
    int lr = lane & 15, lg = lane >> 4;
    const unsigned short* ap = att_pad + n*2560;
    s16x8 a[5];
    #pragma unroll
    for (int mf=0; mf<5; ++mf) a[mf] = *(const s16x8*)&ap[(mf*16+lr)*32 + lg*8];
    int rowoff[5][4];
    #pragma unroll
    for (int mf=0; mf<5; ++mf)
        #pragma unroll
        for (int r=0; r<4; ++r){
            int m = mf*16 + lg*4 + r;
            int s = m/25, v = m - s*25;
            rowoff[mf][r] = (m < 75) ? (v*384 + s*128 + lr) : -1;
        }
    #pragma unroll
    for (int ti=0; ti<2; ++ti){
        int t = tb*8 + w*2 + ti;
        const unsigned short* bp = xbu + (size_t)n*524288 + (size_t)t*4096;
        size_t obase = ((size_t)(n*3350 + 75 + t*25))*384;
        #pragma unroll
        for (int h=0; h<2; ++h){
            s16x8 b[4];
            #pragma unroll
            for (int q=0; q<4; ++q){
                b[q] = *(const s16x8*)&bp[(h*64 + q*16 + lr)*32 + lg*8];
                if (lg == 3){
                    s16x8 t2 = b[q];
                    b[q] = (s16x8){t2[0],0,0,0,0,0,0,0};
                }
            }
            f32x4 acc[5][4];
            #pragma unroll
            for (int mf=0; mf<5; ++mf)
                #pragma unroll
                for (int q=0; q<4; ++q)
                    acc[mf][q] = (f32x4){0.f,0.f,0.f,0.f};
            #pragma unroll
            for (int mf=0; mf<5; ++mf)
                #pragma unroll
                for (int q=0; q<4; ++q)
                    acc[mf][q] = __builtin_amdgcn_mfma_f32_16x16x32_bf16(a[mf], b[q], acc[mf][q], 0, 0, 0);
            #pragma unroll
            for (int mf=0; mf<5; ++mf)
                #pragma unroll
                for (int q=0; q<4; ++q)
                    #pragma unroll
                    for (int r=0; r<4; ++r)
                        if (rowoff[mf][r] >= 0)
                            ypad[obase + rowoff[mf][r] + h*64 + q*16] = f2bf(acc[mf][q][r]);
        }
    }
}

// ---------------- fused conv+ff GEMM v8: v6 + 32 KB LDS (5 blocks/CU) via XOR-swizzled stride-128 tile ----------------
__global__ __launch_bounds__(256,3) void gemm_fused(const unsigned short* __restrict__ Amat,
                                                    const unsigned short* __restrict__ Bsrc,
                                                    const float* __restrict__ xin,
                                                    const float* __restrict__ consts,
                                                    const unsigned short* __restrict__ ffA,
                                                    const float* __restrict__ wbpart,
                                                    const float* __restrict__ asum,
                                                    float* __restrict__ outf)
{
    constexpr int NKB = 42;                   // 42 K-steps of BK=64
    __shared__ unsigned short smem[16384];    // exactly 32 KB: loop A+B; epilogue 128x128 swizzled tile

    const int tid = threadIdx.x;
    const int bid = blockIdx.x;
    const int n   = bid/25;
    const int jn0 = (bid%25)*128;

    const int lane = tid & 63, wv = tid >> 6;
    const int wm = wv >> 1, wn = wv & 1;
    const int lr = lane & 15, lg = lane >> 4;
    const int swz = (lg ^ (lr&3)) << 3;       // read swizzle within each 32-short half

    unsigned short* sA = smem;
    unsigned short* sB = smem + 8192;

    auto stage = [&](int kb){
        #pragma unroll
        for (int p=0; p<4; ++p){
            int e = p*256 + tid;
            int r = e >> 3, cch = e & 7;
            int half = cch >> 2, cc = (cch&3) ^ (r&3);
            stage16(Amat + (size_t)r*2688 + kb*64 + half*32 + cc*8, sA + e*8);
        }
        int k32a = 2*kb, k32b = 2*kb + 1;
        int k0 = k32a % 7, s0 = (k32a/7)*32;
        int k1 = k32b % 7, s1 = (k32b/7)*32;
        const unsigned short* b0 = Bsrc + ((size_t)(n*3350 + jn0 + 25*k0))*384 + s0;
        const unsigned short* b1 = Bsrc + ((size_t)(n*3350 + jn0 + 25*k1))*384 + s1;
        #pragma unroll
        for (int p=0; p<4; ++p){
            int e = p*256 + tid;
            int r = e >> 3, cch = e & 7;
            int half = cch >> 2, cc = (cch&3) ^ (r&3);
            const unsigned short* src = (half ? b1 : b0) + (size_t)r*384 + cc*8;
            stage16(src, sB + e*8);
        }
    };

    f32x4 acc[4][4];
    #pragma unroll
    for (int a2=0;a2<4;a2++)
        #pragma unroll
        for (int b2=0;b2<4;b2++) acc[a2][b2] = (f32x4){0.f,0.f,0.f,0.f};

    for (int kb=0; kb<NKB; ++kb){
        stage(kb);
        __syncthreads();
        s16x8 a[4][2], b[4][2];
        #pragma unroll
        for (int mf=0; mf<4; ++mf)
            #pragma unroll
            for (int kf=0; kf<2; ++kf)
                a[mf][kf] = *(const s16x8*)&sA[(wm*64+mf*16+lr)*64 + kf*32 + swz];
        #pragma unroll
        for (int nf=0; nf<4; ++nf)
            #pragma unroll
            for (int kf=0; kf<2; ++kf)
                b[nf][kf] = *(const s16x8*)&sB[(wn*64+nf*16+lr)*64 + kf*32 + swz];
        __builtin_amdgcn_s_setprio(1);
        #pragma unroll
        for (int kf=0; kf<2; ++kf)
            #pragma unroll
            for (int mf=0; mf<4; ++mf)
                #pragma unroll
                for (int nf=0; nf<4; ++nf)
                    acc[mf][nf] = __builtin_amdgcn_mfma_f32_16x16x32_bf16(a[mf][kf], b[nf][kf], acc[mf][nf], 0, 0, 0);
        __builtin_amdgcn_s_setprio(0);
        __syncthreads();
    }

    // ---------- epilogue: conv BN + v_b-term + residual + leaky -> swizzled [cj][m^((cj&7)<<4)] tile ----------
    const float* asn = asum + n*75;
    #pragma unroll
    for (int nf=0; nf<4; ++nf){
        int cj = wn*64 + nf*16 + lr;
        int j  = jn0 + cj;
        int t  = j/25, v = j - t*25;
        int tc = (t<3) ? t : ((t>124) ? (t-121) : 3);
        float a0 = asn[v], a1 = asn[25+v], a2 = asn[50+v];
        int cx = (cj&7) << 4;
        #pragma unroll
        for (int mf=0; mf<4; ++mf)
            #pragma unroll
            for (int r=0; r<4; ++r){
                int m = wm*64 + mf*16 + lg*4 + r;
                float b2v = wbpart[m*21+tc]*a0 + wbpart[m*21+7+tc]*a1 + wbpart[m*21+14+tc]*a2;
                float val = acc[mf][nf][r]*consts[m] + consts[128+m] + b2v
                          + xin[(size_t)n*409600 + (size_t)m*3200 + j];
                val = (val >= 0.f) ? val : 0.1f*val;
                smem[cj*128 + (m ^ cx)] = f2bf(val);
            }
    }
    __syncthreads();

    // ff GEMM: out2 = ffA @ tile (K = 128 over conv channels), swizzled B reads
    f32x4 acc2[4][4];
    #pragma unroll
    for (int a2=0;a2<4;a2++)
        #pragma unroll
        for (int b2=0;b2<4;b2++) acc2[a2][b2] = (f32x4){0.f,0.f,0.f,0.f};
    #pragma unroll
    for (int kb2=0; kb2<4; ++kb2){
        s16x8 a2[4], b2[4];
        #pragma unroll
        for (int mf=0; mf<4; ++mf)
            a2[mf] = *(const s16x8*)&ffA[(size_t)(wm*64+mf*16+lr)*128 + kb2*32 + lg*8];
        #pragma unroll
        for (int nf=0; nf<4; ++nf){
            int rr = wn*64 + nf*16 + lr;
            b2[nf] = *(const s16x8*)&smem[rr*128 + ((kb2*32 + lg*8) ^ ((rr&7)<<4))];
        }
        #pragma unroll
        for (int mf=0; mf<4; ++mf)
            #pragma unroll
            for (int nf=0; nf<4; ++nf)
                acc2[mf][nf] = __builtin_amdgcn_mfma_f32_16x16x32_bf16(a2[mf], b2[nf], acc2[mf][nf], 0, 0, 0);
    }

    #pragma unroll
    for (int mf=0; mf<4; ++mf)
        #pragma unroll
        for (int r=0; r<4; ++r){
            int co = wm*64 + mf*16 + lg*4 + r;
            float sc2 = consts[256+co], bi2 = consts[384+co];
            #pragma unroll
            for (int nf=0; nf<4; ++nf){
                int cj = wn*64 + nf*16 + lr;
                size_t idx = (size_t)n*409600 + (size_t)co*3200 + jn0 + cj;
                float val = acc2[mf][nf][r]*sc2 + bi2 + xin[idx];
                val = (val >= 0.f) ? val : 0.1f*val;
                outf[idx] = val;
            }
        }
}

extern "C" void kernel_launch(void* const* d_in, const int* in_sizes, int n_in,
                              void* d_out, int out_size, void* d_ws, size_t ws_size,
                              hipStream_t stream) {
    const float* x      = (const float*)d_in[0];
    const float* theta  = (const float*)d_in[1];
    const float* atts   = (const float*)d_in[2];
    const float* alphas = (const float*)d_in[3];
    const float* v_w    = (const float*)d_in[4];
    const float* v_b    = (const float*)d_in[5];
    const float* out_w  = (const float*)d_in[6];
    const float* out_b  = (const float*)d_in[7];
    const float* out_g  = (const float*)d_in[8];
    const float* out_be = (const float*)d_in[9];
    const float* out_m  = (const float*)d_in[10];
    const float* out_v  = (const float*)d_in[11];
    const float* ff_w   = (const float*)d_in[12];
    const float* ff_b   = (const float*)d_in[13];
    const float* ff_g   = (const float*)d_in[14];
    const float* ff_be  = (const float*)d_in[15];
    const float* ff_m   = (const float*)d_in[16];
    const float* ff_v   = (const float*)d_in[17];
    float* out = (float*)d_out;

    char* w = (char*)d_ws;
    size_t off = 0;
    auto alloc = [&](size_t b){ size_t r = off; off += (b + 1023) & ~(size_t)1023; return r; };
    float*          G      = (float*)         (w + alloc(160000));
    float*          SX     = (float*)         (w + alloc(819200));
    float*          nmaxb  = (float*)         (w + alloc(256));
    float*          asumb  = (float*)         (w + alloc(19200));
    float*          consts = (float*)         (w + alloc(2048));
    float*          wbpart = (float*)         (w + alloc(10752));
    float*          pebg   = (float*)         (w + alloc(12800));
    float*          TPgb   = (float*)         (w + alloc(2500));
    unsigned short* att_pad= (unsigned short*)(w + alloc(327680));
    unsigned short* Wr     = (unsigned short*)(w + alloc(688128));
    unsigned short* ffA    = (unsigned short*)(w + alloc(32768));
    unsigned short* xbt    = (unsigned short*)(w + alloc(52428800 + 16384));
    unsigned short* xbu    = (unsigned short*)(w + alloc(67108864));
    unsigned short* ypad   = (unsigned short*)(w + alloc(164659200));

    setup_kernel<<<9344,256,0,stream>>>(x, out_w, ff_w, v_w, v_b, out_b, out_g, out_be, out_m, out_v,
                                        ff_b, ff_g, ff_be, ff_m, ff_v,
                                        consts, ffA, ypad, wbpart, pebg, TPgb, Wr, xbt, xbu, G, SX);
    gram_part<<<512,256,0,stream>>>(xbt, G, SX);
    gram_fin<<<64,256,0,stream>>>(SX, pebg, TPgb, G, nmaxb);
    attn_kernel<<<64,128,0,stream>>>(G, nmaxb, theta, atts, alphas, att_pad, asumb);
    agg_mfma<<<1024,256,0,stream>>>(att_pad, xbu, ypad);
    gemm_fused<<<1600,256,0,stream>>>(Wr, ypad, x, consts, ffA, wbpart, asumb, out);
}

// Round 15
// 498.265 us; speedup vs baseline: 2.4270x; 1.2981x over previous
//
#include <hip/hip_runtime.h>
#include <hip/hip_bf16.h>
#include <math.h>

typedef __attribute__((ext_vector_type(8))) short s16x8;
typedef __attribute__((ext_vector_type(4))) float f32x4;

static __device__ __forceinline__ float bf2f(unsigned short u){
    unsigned int x = ((unsigned int)u) << 16; float f; __builtin_memcpy(&f,&x,4); return f;
}
static __device__ __forceinline__ unsigned short f2bf(float f){
    unsigned int x; __builtin_memcpy(&x,&f,4);
    unsigned int r = (x + 0x7FFFu + ((x>>16)&1u)) >> 16; return (unsigned short)r;
}

static __device__ __forceinline__ void stage16(const void* g, void* l){
    __builtin_amdgcn_global_load_lds((const __attribute__((address_space(1))) unsigned int*)g,
                                     (__attribute__((address_space(3))) unsigned int*)l, 16, 0, 0);
}

// ---------------- sizes ----------------
// N=64, C=128, T=128, V=25, S=3, K=7
// JN = 3200, NTV = 204800, PADROW = 3350, K-dim = 384*7 = 2688

// ---------------- setup: xt (0..6399) + wfold (6400..7295) + prep (7296..9343) ----------------
__global__ __launch_bounds__(256) void setup_kernel(const float* __restrict__ x,
                            const float* __restrict__ out_w, const float* __restrict__ ff_w,
                            const float* __restrict__ v_w,  const float* __restrict__ v_b,
                            const float* __restrict__ out_b, const float* __restrict__ out_g,
                            const float* __restrict__ out_be, const float* __restrict__ out_m,
                            const float* __restrict__ out_v,
                            const float* __restrict__ ff_b, const float* __restrict__ ff_g,
                            const float* __restrict__ ff_be, const float* __restrict__ ff_m,
                            const float* __restrict__ ff_v,
                            float* __restrict__ consts, unsigned short* __restrict__ ffA,
                            unsigned short* __restrict__ ypad, float* __restrict__ wbpart,
                            float* __restrict__ pebg, float* __restrict__ TPgb,
                            unsigned short* __restrict__ Wr,
                            unsigned short* __restrict__ xbt, unsigned short* __restrict__ xbu,
                            float* __restrict__ G, float* __restrict__ SX)
{
    __shared__ float tile[64][65];
    const int bid = blockIdx.x;
    const int tid = threadIdx.x;

    if (bid < 6400){
        int jb = bid % 50; int cb = (bid/50) & 1; int n = bid/100;
        int lane = tid & 63, wv = tid >> 6;
        size_t xbase = (size_t)n*409600;
        int jn = jb*64 + lane;
        int tt = jn/25, uu = jn - tt*25;
        size_t xbu_lb = (size_t)n*524288 + (size_t)tt*4096 + uu;
        #pragma unroll
        for (int r=wv; r<64; r+=4){
            float v = x[xbase + (size_t)(cb*64+r)*3200 + jb*64 + lane];
            tile[r][lane] = v;
            xbu[xbu_lb + (size_t)(cb*64+r)*32] = f2bf(v);
        }
        __syncthreads();
        #pragma unroll
        for (int j=wv; j<64; j+=4)
            xbt[xbase + (size_t)(jb*64+j)*128 + cb*64 + lane] = f2bf(tile[lane][j]);
        return;
    }

    if (bid < 7296){
        float* owl = &tile[0][0];
        int wb = bid - 6400;
        int o = wb/7, k = wb%7;
        for (int i=tid; i<384; i+=256) owl[i] = out_w[(size_t)(o*384 + i)*7 + k];
        __syncthreads();
        for (int sci=tid; sci<384; sci+=256){
            int s = sci >> 7, ci = sci & 127;
            const float* ow = owl + s*128;
            float acc = 0.f;
            #pragma unroll 8
            for (int c=0; c<128; ++c) acc += ow[c] * v_w[c*128 + ci];
            int kb = (sci>>5)*7 + k, jj = sci & 31;
            Wr[(size_t)o*2688 + kb*32 + jj] = f2bf(acc);
        }
        return;
    }

    // ---- prep ----
    const int stride = 2048*256;
    int i0 = (bid-7296)*256 + tid;
    const float KLN = 9.210340371976184f/128.f;   // ln(1e4)/C
    for (int i=i0; i<40000;  i+=stride) G[i]  = 0.f;
    for (int i=i0; i<204800; i+=stride) SX[i] = 0.f;
    for (int i=i0; i<16384; i+=stride) ffA[i] = f2bf(ff_w[i]);
    for (int i=i0; i<128; i+=stride){
        float inv  = out_g[i]/sqrtf(out_v[i]+1e-5f);
        consts[i]       = inv;
        consts[128+i]   = out_b[i]*inv + out_be[i] - out_m[i]*inv;
        float invf = ff_g[i]/sqrtf(ff_v[i]+1e-5f);
        consts[256+i]   = invf;
        consts[384+i]   = ff_b[i]*invf + ff_be[i] - ff_m[i]*invf;
    }
    for (int i=i0; i<3200; i+=stride){
        int v = i >> 7, c = i & 127;
        float freq = expf(-(float)(c & ~1) * KLN);
        float ang = (float)v * freq;
        pebg[i] = (c & 1) ? cosf(ang) : sinf(ang);
    }
    for (int i=i0; i<625; i+=stride){
        int u = i/25, v = i%25;
        float acc = 0.f;
        for (int c=0; c<128; ++c){
            float freq = expf(-(float)(c & ~1) * KLN);
            float pu = (c & 1) ? cosf((float)u*freq) : sinf((float)u*freq);
            float pv = (c & 1) ? cosf((float)v*freq) : sinf((float)v*freq);
            acc += pu*pv;
        }
        TPgb[i] = 128.f*acc;
    }
    for (int i=i0; i<2688; i+=stride){
        int o = i/21, rem = i%21, s = rem/7, tc = rem%7;
        int kmin = (tc<3) ? (3-tc) : 0;
        int kmax = (tc>3) ? (10-tc) : 7;
        float acc = 0.f;
        for (int c=0; c<128; ++c){
            const float* wp = out_w + (size_t)(o*384 + s*128 + c)*7;
            float vb = v_b[c];
            for (int k=kmin; k<kmax; ++k) acc += wp[k]*vb;
        }
        wbpart[i] = acc;
    }
    // zero the temporal halo pads of Ypad
    for (int i=i0; i<3686400; i+=stride){
        int n2 = i/57600, r2 = i%57600;
        int pp = r2/384, sc = r2%384;
        int ppos = (pp < 75) ? pp : (3200 + pp);
        ypad[(size_t)(n2*3350 + ppos)*384 + sc] = 0;
    }
    // NOTE: xbu u-pads (u=25..31) left as garbage; agg_mfma masks them in-register.
}

// ---------------- gram part: partial Gx (MFMA) + partial sx, atomics, 512 blocks ----------------
__global__ __launch_bounds__(256) void gram_part(const unsigned short* __restrict__ xbt,
                                                 float* __restrict__ G, float* __restrict__ SX){
    __shared__ float glx[4][32][32];
    int bid = blockIdx.x; int n = bid >> 3; int chunk = bid & 7;
    int tid = threadIdx.x;
    const unsigned short* xb = xbt + (size_t)n*409600;

    int c = tid & 127, th = tid >> 7;
    float a[25];
    #pragma unroll
    for (int u=0; u<25; ++u) a[u] = 0.f;
    for (int tt=0; tt<8; ++tt){
        int t = chunk*16 + th*8 + tt;
        const unsigned short* row = xb + (size_t)t*3200 + c;
        #pragma unroll
        for (int u=0; u<25; ++u) a[u] += bf2f(row[u*128]);
    }
    float* tmp = &glx[0][0][0];
    if (th){
        #pragma unroll
        for (int u=0; u<25; ++u) tmp[u*128+c] = a[u];
    }
    __syncthreads();
    if (!th){
        #pragma unroll
        for (int u=0; u<25; ++u) atomicAdd(&SX[n*3200 + u*128 + c], a[u] + tmp[u*128+c]);
    }
    __syncthreads();

    int lane = tid & 63, w = tid >> 6;
    int lr = lane & 15, lg = lane >> 4;
    f32x4 acc[2][2];
    #pragma unroll
    for (int i2=0;i2<2;i2++)
        #pragma unroll
        for (int j2=0;j2<2;j2++) acc[i2][j2] = (f32x4){0.f,0.f,0.f,0.f};
    for (int tt=0; tt<4; ++tt){
        int t = chunk*16 + w*4 + tt;
        const unsigned short* tb = xb + (size_t)t*3200;
        #pragma unroll
        for (int kc=0; kc<4; ++kc){
            s16x8 f0 = *(const s16x8*)(tb + (size_t)(lr)*128    + kc*32 + lg*8);
            s16x8 f1 = *(const s16x8*)(tb + (size_t)(16+lr)*128 + kc*32 + lg*8);
            acc[0][0] = __builtin_amdgcn_mfma_f32_16x16x32_bf16(f0, f0, acc[0][0], 0,0,0);
            acc[0][1] = __builtin_amdgcn_mfma_f32_16x16x32_bf16(f0, f1, acc[0][1], 0,0,0);
            acc[1][0] = __builtin_amdgcn_mfma_f32_16x16x32_bf16(f1, f0, acc[1][0], 0,0,0);
            acc[1][1] = __builtin_amdgcn_mfma_f32_16x16x32_bf16(f1, f1, acc[1][1], 0,0,0);
        }
    }
    #pragma unroll
    for (int mh=0; mh<2; ++mh)
        #pragma unroll
        for (int nh=0; nh<2; ++nh)
            #pragma unroll
            for (int r=0; r<4; ++r)
                glx[w][mh*16 + lg*4 + r][nh*16 + lr] = acc[mh][nh][r];
    __syncthreads();
    for (int idx=tid; idx<625; idx+=256){
        int u = idx/25, v = idx%25;
        atomicAdd(&G[n*625 + idx], glx[0][u][v] + glx[1][u][v] + glx[2][u][v] + glx[3][u][v]);
    }
}

// ---------------- gram fin: G += pe correction; also per-n d2 max ----------------
__global__ __launch_bounds__(256) void gram_fin(const float* __restrict__ SX,
                                                const float* __restrict__ pebg,
                                                const float* __restrict__ TPgb,
                                                float* __restrict__ G,
                                                float* __restrict__ nmax){
    __shared__ float sxl[25][129];
    __shared__ float pebl[25][129];
    __shared__ float gf[625];
    __shared__ float red[256];
    int n = blockIdx.x, tid = threadIdx.x;
    for (int i=tid; i<3200; i+=256){
        sxl[i>>7][i&127]  = SX[n*3200 + i];
        pebl[i>>7][i&127] = pebg[i];
    }
    __syncthreads();
    for (int idx=tid; idx<625; idx+=256){
        int u = idx/25, v = idx%25;
        float cr = TPgb[idx];
        #pragma unroll 4
        for (int cc=0; cc<128; ++cc)
            cr += sxl[u][cc]*pebl[v][cc] + sxl[v][cc]*pebl[u][cc];
        float val = G[n*625 + idx] + cr;
        G[n*625 + idx] = val;
        gf[idx] = val;
    }
    __syncthreads();
    float mx = 0.f;
    for (int idx=tid; idx<625; idx+=256){
        int u = idx/25, v = idx%25;
        float d2 = fmaxf(gf[u*26] + gf[v*26] - 2.f*gf[u*25+v], 0.f);
        mx = fmaxf(mx, d2);
    }
    red[tid] = mx; __syncthreads();
    for (int s2=128; s2>0; s2>>=1){ if (tid < s2) red[tid] = fmaxf(red[tid], red[tid+s2]); __syncthreads(); }
    if (tid == 0) nmax[n] = red[0];
}

// ---------------- attention: 64 blocks (one per n) ----------------
__global__ __launch_bounds__(128) void attn_kernel(const float* __restrict__ G, const float* __restrict__ nmax,
                                                   const float* __restrict__ theta,
                                                   const float* __restrict__ atts, const float* __restrict__ alphas,
                                                   unsigned short* __restrict__ att_pad, float* __restrict__ asum){
    __shared__ float gl[625];
    __shared__ float red[64];
    int n = blockIdx.x, tid = threadIdx.x;
    if (tid < 64) red[tid] = nmax[tid];
    for (int i=tid; i<625; i+=128) gl[i] = G[n*625 + i];
    __syncthreads();
    if (tid == 0){
        float m = red[0];
        for (int i=1; i<64; ++i) m = fmaxf(m, red[i]);
        red[0] = m;
    }
    __syncthreads();
    float inv = 1.f/red[0];
    for (int i=tid; i<160; i+=128) att_pad[n*2560 + 2400 + i] = 0;
    if (tid < 75){
        int s = tid/25, vc = tid%25;
        float et = expf(theta[s]);
        float al = alphas[s];
        float gvv = gl[vc*26];
        float z[25];
        #pragma unroll
        for (int u2=0; u2<25; ++u2){
            float d2v = fmaxf(gl[u2*26] + gvv - 2.f*gl[u2*25+vc], 0.f);
            z[u2] = expf(-et*d2v*inv);
        }
        float zm = z[0];
        #pragma unroll
        for (int u2=1; u2<25; ++u2) zm = fmaxf(zm, z[u2]);
        float lo = zm - 1.f, hi = zm;
        for (int it=0; it<30; ++it){
            float mid = 0.5f*(lo+hi);
            float f = 0.f;
            #pragma unroll
            for (int u2=0; u2<25; ++u2) f += fmaxf(z[u2]-mid, 0.f);
            if (f >= 1.f) lo = mid; else hi = mid;
        }
        float ssum = 0.f; int kcnt = 0;
        #pragma unroll
        for (int u2=0; u2<25; ++u2){ if (z[u2] > lo){ ssum += z[u2]; kcnt++; } }
        float tau = (ssum - 1.f)/(float)kcnt;
        float as_ = 0.f;
        unsigned short* apr = att_pad + n*2560 + (s*25+vc)*32;
        #pragma unroll
        for (int u2=0; u2<25; ++u2){
            float av = atts[s*625 + u2*25 + vc] + fmaxf(z[u2]-tau, 0.f)*al;
            apr[u2] = f2bf(av);
            as_ += av;
        }
        #pragma unroll
        for (int u2=25; u2<32; ++u2) apr[u2] = 0;
        asum[n*75 + s*25 + vc] = as_;
    }
}

// ---------------- agg via MFMA (xbu u-pads masked in-register) ----------------
__global__ __launch_bounds__(256,2) void agg_mfma(const unsigned short* __restrict__ att_pad,
                                                  const unsigned short* __restrict__ xbu,
                                                  unsigned short* __restrict__ ypad){
    int bid = blockIdx.x; int n = bid >> 4; int tb = bid & 15;
    int tid = threadIdx.x; int lane = tid & 63; int w = tid >> 6;
    int lr = lane & 15, lg = lane >> 4;
    const unsigned short* ap = att_pad + n*2560;
    s16x8 a[5];
    #pragma unroll
    for (int mf=0; mf<5; ++mf) a[mf] = *(const s16x8*)&ap[(mf*16+lr)*32 + lg*8];
    int rowoff[5][4];
    #pragma unroll
    for (int mf=0; mf<5; ++mf)
        #pragma unroll
        for (int r=0; r<4; ++r){
            int m = mf*16 + lg*4 + r;
            int s = m/25, v = m - s*25;
            rowoff[mf][r] = (m < 75) ? (v*384 + s*128 + lr) : -1;
        }
    #pragma unroll
    for (int ti=0; ti<2; ++ti){
        int t = tb*8 + w*2 + ti;
        const unsigned short* bp = xbu + (size_t)n*524288 + (size_t)t*4096;
        size_t obase = ((size_t)(n*3350 + 75 + t*25))*384;
        #pragma unroll
        for (int h=0; h<2; ++h){
            s16x8 b[4];
            #pragma unroll
            for (int q=0; q<4; ++q){
                b[q] = *(const s16x8*)&bp[(h*64 + q*16 + lr)*32 + lg*8];
                if (lg == 3){
                    s16x8 t2 = b[q];
                    b[q] = (s16x8){t2[0],0,0,0,0,0,0,0};
                }
            }
            f32x4 acc[5][4];
            #pragma unroll
            for (int mf=0; mf<5; ++mf)
                #pragma unroll
                for (int q=0; q<4; ++q)
                    acc[mf][q] = (f32x4){0.f,0.f,0.f,0.f};
            #pragma unroll
            for (int mf=0; mf<5; ++mf)
                #pragma unroll
                for (int q=0; q<4; ++q)
                    acc[mf][q] = __builtin_amdgcn_mfma_f32_16x16x32_bf16(a[mf], b[q], acc[mf][q], 0, 0, 0);
            #pragma unroll
            for (int mf=0; mf<5; ++mf)
                #pragma unroll
                for (int q=0; q<4; ++q)
                    #pragma unroll
                    for (int r=0; r<4; ++r)
                        if (rowoff[mf][r] >= 0)
                            ypad[obase + rowoff[mf][r] + h*64 + q*16] = f2bf(acc[mf][q][r]);
        }
    }
}

// ---------------- fused conv+ff GEMM v6: BK=64, 35 KB LDS, launch_bounds(256,3) ----------------
__global__ __launch_bounds__(256,3) void gemm_fused(const unsigned short* __restrict__ Amat,
                                                    const unsigned short* __restrict__ Bsrc,
                                                    const float* __restrict__ xin,
                                                    const float* __restrict__ consts,
                                                    const unsigned short* __restrict__ ffA,
                                                    const float* __restrict__ wbpart,
                                                    const float* __restrict__ asum,
                                                    float* __restrict__ outf)
{
    constexpr int NKB = 42;                   // 42 K-steps of BK=64
    __shared__ unsigned short smem[17560];    // loop: A(16KB)+B(16KB); epilogue: tile 34.8KB + asl 300B

    const int tid = threadIdx.x;
    const int bid = blockIdx.x;
    const int n   = bid/25;
    const int jn0 = (bid%25)*128;

    const int lane = tid & 63, wv = tid >> 6;
    const int wm = wv >> 1, wn = wv & 1;
    const int lr = lane & 15, lg = lane >> 4;
    const int swz = (lg ^ (lr&3)) << 3;       // read swizzle within each 32-short half

    unsigned short* sA = smem;
    unsigned short* sB = smem + 8192;

    auto stage = [&](int kb){
        #pragma unroll
        for (int p=0; p<4; ++p){
            int e = p*256 + tid;
            int r = e >> 3, cch = e & 7;
            int half = cch >> 2, cc = (cch&3) ^ (r&3);
            stage16(Amat + (size_t)r*2688 + kb*64 + half*32 + cc*8, sA + e*8);
        }
        int k32a = 2*kb, k32b = 2*kb + 1;
        int k0 = k32a % 7, s0 = (k32a/7)*32;
        int k1 = k32b % 7, s1 = (k32b/7)*32;
        const unsigned short* b0 = Bsrc + ((size_t)(n*3350 + jn0 + 25*k0))*384 + s0;
        const unsigned short* b1 = Bsrc + ((size_t)(n*3350 + jn0 + 25*k1))*384 + s1;
        #pragma unroll
        for (int p=0; p<4; ++p){
            int e = p*256 + tid;
            int r = e >> 3, cch = e & 7;
            int half = cch >> 2, cc = (cch&3) ^ (r&3);
            const unsigned short* src = (half ? b1 : b0) + (size_t)r*384 + cc*8;
            stage16(src, sB + e*8);
        }
    };

    f32x4 acc[4][4];
    #pragma unroll
    for (int a2=0;a2<4;a2++)
        #pragma unroll
        for (int b2=0;b2<4;b2++) acc[a2][b2] = (f32x4){0.f,0.f,0.f,0.f};

    for (int kb=0; kb<NKB; ++kb){
        stage(kb);
        __syncthreads();
        s16x8 a[4][2], b[4][2];
        #pragma unroll
        for (int mf=0; mf<4; ++mf)
            #pragma unroll
            for (int kf=0; kf<2; ++kf)
                a[mf][kf] = *(const s16x8*)&sA[(wm*64+mf*16+lr)*64 + kf*32 + swz];
        #pragma unroll
        for (int nf=0; nf<4; ++nf)
            #pragma unroll
            for (int kf=0; kf<2; ++kf)
                b[nf][kf] = *(const s16x8*)&sB[(wn*64+nf*16+lr)*64 + kf*32 + swz];
        __builtin_amdgcn_s_setprio(1);
        #pragma unroll
        for (int kf=0; kf<2; ++kf)
            #pragma unroll
            for (int mf=0; mf<4; ++mf)
                #pragma unroll
                for (int nf=0; nf<4; ++nf)
                    acc[mf][nf] = __builtin_amdgcn_mfma_f32_16x16x32_bf16(a[mf][kf], b[nf][kf], acc[mf][nf], 0, 0, 0);
        __builtin_amdgcn_s_setprio(0);
        __syncthreads();
    }

    float* asl = (float*)(smem + 17408);   // 75 floats, above the 34.8KB tile
    for (int i=tid; i<75; i+=256) asl[i] = asum[n*75 + i];
    __syncthreads();

    #pragma unroll
    for (int nf=0; nf<4; ++nf){
        int cj = wn*64 + nf*16 + lr;
        int j  = jn0 + cj;
        int t  = j/25, v = j - t*25;
        int tc = (t<3) ? t : ((t>124) ? (t-121) : 3);
        float a0 = asl[v], a1 = asl[25+v], a2 = asl[50+v];
        #pragma unroll
        for (int mf=0; mf<4; ++mf)
            #pragma unroll
            for (int r=0; r<4; ++r){
                int m = wm*64 + mf*16 + lg*4 + r;
                float b2v = wbpart[m*21+tc]*a0 + wbpart[m*21+7+tc]*a1 + wbpart[m*21+14+tc]*a2;
                float val = acc[mf][nf][r]*consts[m] + consts[128+m] + b2v
                          + xin[(size_t)n*409600 + (size_t)m*3200 + j];
                val = (val >= 0.f) ? val : 0.1f*val;
                smem[cj*136 + m] = f2bf(val);
            }
    }
    __syncthreads();

    f32x4 acc2[4][4];
    #pragma unroll
    for (int a2=0;a2<4;a2++)
        #pragma unroll
        for (int b2=0;b2<4;b2++) acc2[a2][b2] = (f32x4){0.f,0.f,0.f,0.f};
    #pragma unroll
    for (int kb2=0; kb2<4; ++kb2){
        s16x8 a2[4], b2[4];
        #pragma unroll
        for (int mf=0; mf<4; ++mf)
            a2[mf] = *(const s16x8*)&ffA[(size_t)(wm*64+mf*16+lr)*128 + kb2*32 + lg*8];
        #pragma unroll
        for (int nf=0; nf<4; ++nf)
            b2[nf] = *(const s16x8*)&smem[(wn*64+nf*16+lr)*136 + kb2*32 + lg*8];
        #pragma unroll
        for (int mf=0; mf<4; ++mf)
            #pragma unroll
            for (int nf=0; nf<4; ++nf)
                acc2[mf][nf] = __builtin_amdgcn_mfma_f32_16x16x32_bf16(a2[mf], b2[nf], acc2[mf][nf], 0, 0, 0);
    }

    #pragma unroll
    for (int mf=0; mf<4; ++mf)
        #pragma unroll
        for (int r=0; r<4; ++r){
            int co = wm*64 + mf*16 + lg*4 + r;
            float sc2 = consts[256+co], bi2 = consts[384+co];
            #pragma unroll
            for (int nf=0; nf<4; ++nf){
                int cj = wn*64 + nf*16 + lr;
                size_t idx = (size_t)n*409600 + (size_t)co*3200 + jn0 + cj;
                float val = acc2[mf][nf][r]*sc2 + bi2 + xin[idx];
                val = (val >= 0.f) ? val : 0.1f*val;
                outf[idx] = val;
            }
        }
}

extern "C" void kernel_launch(void* const* d_in, const int* in_sizes, int n_in,
                              void* d_out, int out_size, void* d_ws, size_t ws_size,
                              hipStream_t stream) {
    const float* x      = (const float*)d_in[0];
    const float* theta  = (const float*)d_in[1];
    const float* atts   = (const float*)d_in[2];
    const float* alphas = (const float*)d_in[3];
    const float* v_w    = (const float*)d_in[4];
    const float* v_b    = (const float*)d_in[5];
    const float* out_w  = (const float*)d_in[6];
    const float* out_b  = (const float*)d_in[7];
    const float* out_g  = (const float*)d_in[8];
    const float* out_be = (const float*)d_in[9];
    const float* out_m  = (const float*)d_in[10];
    const float* out_v  = (const float*)d_in[11];
    const float* ff_w   = (const float*)d_in[12];
    const float* ff_b   = (const float*)d_in[13];
    const float* ff_g   = (const float*)d_in[14];
    const float* ff_be  = (const float*)d_in[15];
    const float* ff_m   = (const float*)d_in[16];
    const float* ff_v   = (const float*)d_in[17];
    float* out = (float*)d_out;

    char* w = (char*)d_ws;
    size_t off = 0;
    auto alloc = [&](size_t b){ size_t r = off; off += (b + 1023) & ~(size_t)1023; return r; };
    float*          G      = (float*)         (w + alloc(160000));
    float*          SX     = (float*)         (w + alloc(819200));
    float*          nmaxb  = (float*)         (w + alloc(256));
    float*          asumb  = (float*)         (w + alloc(19200));
    float*          consts = (float*)         (w + alloc(2048));
    float*          wbpart = (float*)         (w + alloc(10752));
    float*          pebg   = (float*)         (w + alloc(12800));
    float*          TPgb   = (float*)         (w + alloc(2500));
    unsigned short* att_pad= (unsigned short*)(w + alloc(327680));
    unsigned short* Wr     = (unsigned short*)(w + alloc(688128));
    unsigned short* ffA    = (unsigned short*)(w + alloc(32768));
    unsigned short* xbt    = (unsigned short*)(w + alloc(52428800 + 16384));
    unsigned short* xbu    = (unsigned short*)(w + alloc(67108864));
    unsigned short* ypad   = (unsigned short*)(w + alloc(164659200));

    setup_kernel<<<9344,256,0,stream>>>(x, out_w, ff_w, v_w, v_b, out_b, out_g, out_be, out_m, out_v,
                                        ff_b, ff_g, ff_be, ff_m, ff_v,
                                        consts, ffA, ypad, wbpart, pebg, TPgb, Wr, xbt, xbu, G, SX);
    gram_part<<<512,256,0,stream>>>(xbt, G, SX);
    gram_fin<<<64,256,0,stream>>>(SX, pebg, TPgb, G, nmaxb);
    attn_kernel<<<64,128,0,stream>>>(G, nmaxb, theta, atts, alphas, att_pad, asumb);
    agg_mfma<<<1024,256,0,stream>>>(att_pad, xbu, ypad);
    gemm_fused<<<1600,256,0,stream>>>(Wr, ypad, x, consts, ffA, wbpart, asumb, out);
}

// Round 16
// 491.533 us; speedup vs baseline: 2.4603x; 1.0137x over previous
//
#include <hip/hip_runtime.h>
#include <hip/hip_bf16.h>
#include <math.h>

typedef __attribute__((ext_vector_type(8))) short s16x8;
typedef __attribute__((ext_vector_type(4))) float f32x4;

static __device__ __forceinline__ float bf2f(unsigned short u){
    unsigned int x = ((unsigned int)u) << 16; float f; __builtin_memcpy(&f,&x,4); return f;
}
static __device__ __forceinline__ unsigned short f2bf(float f){
    unsigned int x; __builtin_memcpy(&x,&f,4);
    unsigned int r = (x + 0x7FFFu + ((x>>16)&1u)) >> 16; return (unsigned short)r;
}

static __device__ __forceinline__ void stage16(const void* g, void* l){
    __builtin_amdgcn_global_load_lds((const __attribute__((address_space(1))) unsigned int*)g,
                                     (__attribute__((address_space(3))) unsigned int*)l, 16, 0, 0);
}

// ---------------- sizes ----------------
// N=64, C=128, T=128, V=25, S=3, K=7
// JN = 3200, NTV = 204800, PADROW = 3350, K-dim = 384*7 = 2688

// ---------------- setup: xt (0..6399) + wfold (6400..7295) + prep (7296..9343) ----------------
__global__ __launch_bounds__(256) void setup_kernel(const float* __restrict__ x,
                            const float* __restrict__ out_w, const float* __restrict__ ff_w,
                            const float* __restrict__ v_w,  const float* __restrict__ v_b,
                            const float* __restrict__ out_b, const float* __restrict__ out_g,
                            const float* __restrict__ out_be, const float* __restrict__ out_m,
                            const float* __restrict__ out_v,
                            const float* __restrict__ ff_b, const float* __restrict__ ff_g,
                            const float* __restrict__ ff_be, const float* __restrict__ ff_m,
                            const float* __restrict__ ff_v,
                            float* __restrict__ consts, unsigned short* __restrict__ ffA,
                            unsigned short* __restrict__ ypad, float* __restrict__ wbpart,
                            float* __restrict__ pebg, float* __restrict__ TPgb,
                            unsigned short* __restrict__ Wr,
                            unsigned short* __restrict__ xbt, unsigned short* __restrict__ xbu,
                            float* __restrict__ G, float* __restrict__ SX)
{
    __shared__ float tile[64][65];
    const int bid = blockIdx.x;
    const int tid = threadIdx.x;

    if (bid < 6400){
        int jb = bid % 50; int cb = (bid/50) & 1; int n = bid/100;
        int lane = tid & 63, wv = tid >> 6;
        size_t xbase = (size_t)n*409600;
        int jn = jb*64 + lane;
        int tt = jn/25, uu = jn - tt*25;
        size_t xbu_lb = (size_t)n*524288 + (size_t)tt*4096 + uu;
        #pragma unroll
        for (int r=wv; r<64; r+=4){
            float v = x[xbase + (size_t)(cb*64+r)*3200 + jb*64 + lane];
            tile[r][lane] = v;
            xbu[xbu_lb + (size_t)(cb*64+r)*32] = f2bf(v);
        }
        __syncthreads();
        #pragma unroll
        for (int j=wv; j<64; j+=4)
            xbt[xbase + (size_t)(jb*64+j)*128 + cb*64 + lane] = f2bf(tile[lane][j]);
        return;
    }

    if (bid < 7296){
        float* owl = &tile[0][0];
        int wb = bid - 6400;
        int o = wb/7, k = wb%7;
        for (int i=tid; i<384; i+=256) owl[i] = out_w[(size_t)(o*384 + i)*7 + k];
        __syncthreads();
        for (int sci=tid; sci<384; sci+=256){
            int s = sci >> 7, ci = sci & 127;
            const float* ow = owl + s*128;
            float acc = 0.f;
            #pragma unroll 8
            for (int c=0; c<128; ++c) acc += ow[c] * v_w[c*128 + ci];
            int kb = (sci>>5)*7 + k, jj = sci & 31;
            Wr[(size_t)o*2688 + kb*32 + jj] = f2bf(acc);
        }
        return;
    }

    // ---- prep ----
    const int stride = 2048*256;
    int i0 = (bid-7296)*256 + tid;
    const float KLN = 9.210340371976184f/128.f;   // ln(1e4)/C
    for (int i=i0; i<40000;  i+=stride) G[i]  = 0.f;
    for (int i=i0; i<204800; i+=stride) SX[i] = 0.f;
    for (int i=i0; i<16384; i+=stride) ffA[i] = f2bf(ff_w[i]);
    for (int i=i0; i<128; i+=stride){
        float inv  = out_g[i]/sqrtf(out_v[i]+1e-5f);
        consts[i]       = inv;
        consts[128+i]   = out_b[i]*inv + out_be[i] - out_m[i]*inv;
        float invf = ff_g[i]/sqrtf(ff_v[i]+1e-5f);
        consts[256+i]   = invf;
        consts[384+i]   = ff_b[i]*invf + ff_be[i] - ff_m[i]*invf;
    }
    for (int i=i0; i<3200; i+=stride){
        int v = i >> 7, c = i & 127;
        float freq = expf(-(float)(c & ~1) * KLN);
        float ang = (float)v * freq;
        pebg[i] = (c & 1) ? cosf(ang) : sinf(ang);
    }
    for (int i=i0; i<625; i+=stride){
        int u = i/25, v = i%25;
        float acc = 0.f;
        for (int c=0; c<128; ++c){
            float freq = expf(-(float)(c & ~1) * KLN);
            float pu = (c & 1) ? cosf((float)u*freq) : sinf((float)u*freq);
            float pv = (c & 1) ? cosf((float)v*freq) : sinf((float)v*freq);
            acc += pu*pv;
        }
        TPgb[i] = 128.f*acc;
    }
    for (int i=i0; i<2688; i+=stride){
        int o = i/21, rem = i%21, s = rem/7, tc = rem%7;
        int kmin = (tc<3) ? (3-tc) : 0;
        int kmax = (tc>3) ? (10-tc) : 7;
        float acc = 0.f;
        for (int c=0; c<128; ++c){
            const float* wp = out_w + (size_t)(o*384 + s*128 + c)*7;
            float vb = v_b[c];
            for (int k=kmin; k<kmax; ++k) acc += wp[k]*vb;
        }
        wbpart[i] = acc;
    }
    // zero the temporal halo pads of Ypad
    for (int i=i0; i<3686400; i+=stride){
        int n2 = i/57600, r2 = i%57600;
        int pp = r2/384, sc = r2%384;
        int ppos = (pp < 75) ? pp : (3200 + pp);
        ypad[(size_t)(n2*3350 + ppos)*384 + sc] = 0;
    }
    // NOTE: xbu u-pads (u=25..31) left as garbage; agg_mfma masks them in-register.
}

// ---------------- gram part: partial Gx (MFMA) + partial sx, atomics, 512 blocks ----------------
__global__ __launch_bounds__(256) void gram_part(const unsigned short* __restrict__ xbt,
                                                 float* __restrict__ G, float* __restrict__ SX){
    __shared__ float glx[4][32][32];
    int bid = blockIdx.x; int n = bid >> 3; int chunk = bid & 7;
    int tid = threadIdx.x;
    const unsigned short* xb = xbt + (size_t)n*409600;

    int c = tid & 127, th = tid >> 7;
    float a[25];
    #pragma unroll
    for (int u=0; u<25; ++u) a[u] = 0.f;
    for (int tt=0; tt<8; ++tt){
        int t = chunk*16 + th*8 + tt;
        const unsigned short* row = xb + (size_t)t*3200 + c;
        #pragma unroll
        for (int u=0; u<25; ++u) a[u] += bf2f(row[u*128]);
    }
    float* tmp = &glx[0][0][0];
    if (th){
        #pragma unroll
        for (int u=0; u<25; ++u) tmp[u*128+c] = a[u];
    }
    __syncthreads();
    if (!th){
        #pragma unroll
        for (int u=0; u<25; ++u) atomicAdd(&SX[n*3200 + u*128 + c], a[u] + tmp[u*128+c]);
    }
    __syncthreads();

    int lane = tid & 63, w = tid >> 6;
    int lr = lane & 15, lg = lane >> 4;
    f32x4 acc[2][2];
    #pragma unroll
    for (int i2=0;i2<2;i2++)
        #pragma unroll
        for (int j2=0;j2<2;j2++) acc[i2][j2] = (f32x4){0.f,0.f,0.f,0.f};
    for (int tt=0; tt<4; ++tt){
        int t = chunk*16 + w*4 + tt;
        const unsigned short* tb = xb + (size_t)t*3200;
        #pragma unroll
        for (int kc=0; kc<4; ++kc){
            s16x8 f0 = *(const s16x8*)(tb + (size_t)(lr)*128    + kc*32 + lg*8);
            s16x8 f1 = *(const s16x8*)(tb + (size_t)(16+lr)*128 + kc*32 + lg*8);
            acc[0][0] = __builtin_amdgcn_mfma_f32_16x16x32_bf16(f0, f0, acc[0][0], 0,0,0);
            acc[0][1] = __builtin_amdgcn_mfma_f32_16x16x32_bf16(f0, f1, acc[0][1], 0,0,0);
            acc[1][0] = __builtin_amdgcn_mfma_f32_16x16x32_bf16(f1, f0, acc[1][0], 0,0,0);
            acc[1][1] = __builtin_amdgcn_mfma_f32_16x16x32_bf16(f1, f1, acc[1][1], 0,0,0);
        }
    }
    #pragma unroll
    for (int mh=0; mh<2; ++mh)
        #pragma unroll
        for (int nh=0; nh<2; ++nh)
            #pragma unroll
            for (int r=0; r<4; ++r)
                glx[w][mh*16 + lg*4 + r][nh*16 + lr] = acc[mh][nh][r];
    __syncthreads();
    for (int idx=tid; idx<625; idx+=256){
        int u = idx/25, v = idx%25;
        atomicAdd(&G[n*625 + idx], glx[0][u][v] + glx[1][u][v] + glx[2][u][v] + glx[3][u][v]);
    }
}

// ---------------- gram fin: G += pe correction; also per-n d2 max ----------------
__global__ __launch_bounds__(256) void gram_fin(const float* __restrict__ SX,
                                                const float* __restrict__ pebg,
                                                const float* __restrict__ TPgb,
                                                float* __restrict__ G,
                                                float* __restrict__ nmax){
    __shared__ float sxl[25][129];
    __shared__ float pebl[25][129];
    __shared__ float gf[625];
    __shared__ float red[256];
    int n = blockIdx.x, tid = threadIdx.x;
    for (int i=tid; i<3200; i+=256){
        sxl[i>>7][i&127]  = SX[n*3200 + i];
        pebl[i>>7][i&127] = pebg[i];
    }
    __syncthreads();
    for (int idx=tid; idx<625; idx+=256){
        int u = idx/25, v = idx%25;
        float cr = TPgb[idx];
        #pragma unroll 4
        for (int cc=0; cc<128; ++cc)
            cr += sxl[u][cc]*pebl[v][cc] + sxl[v][cc]*pebl[u][cc];
        float val = G[n*625 + idx] + cr;
        G[n*625 + idx] = val;
        gf[idx] = val;
    }
    __syncthreads();
    float mx = 0.f;
    for (int idx=tid; idx<625; idx+=256){
        int u = idx/25, v = idx%25;
        float d2 = fmaxf(gf[u*26] + gf[v*26] - 2.f*gf[u*25+v], 0.f);
        mx = fmaxf(mx, d2);
    }
    red[tid] = mx; __syncthreads();
    for (int s2=128; s2>0; s2>>=1){ if (tid < s2) red[tid] = fmaxf(red[tid], red[tid+s2]); __syncthreads(); }
    if (tid == 0) nmax[n] = red[0];
}

// ---------------- attention: 64 blocks (one per n) ----------------
__global__ __launch_bounds__(128) void attn_kernel(const float* __restrict__ G, const float* __restrict__ nmax,
                                                   const float* __restrict__ theta,
                                                   const float* __restrict__ atts, const float* __restrict__ alphas,
                                                   unsigned short* __restrict__ att_pad, float* __restrict__ asum){
    __shared__ float gl[625];
    __shared__ float red[64];
    int n = blockIdx.x, tid = threadIdx.x;
    if (tid < 64) red[tid] = nmax[tid];
    for (int i=tid; i<625; i+=128) gl[i] = G[n*625 + i];
    __syncthreads();
    if (tid == 0){
        float m = red[0];
        for (int i=1; i<64; ++i) m = fmaxf(m, red[i]);
        red[0] = m;
    }
    __syncthreads();
    float inv = 1.f/red[0];
    for (int i=tid; i<160; i+=128) att_pad[n*2560 + 2400 + i] = 0;
    if (tid < 75){
        int s = tid/25, vc = tid%25;
        float et = expf(theta[s]);
        float al = alphas[s];
        float gvv = gl[vc*26];
        float z[25];
        #pragma unroll
        for (int u2=0; u2<25; ++u2){
            float d2v = fmaxf(gl[u2*26] + gvv - 2.f*gl[u2*25+vc], 0.f);
            z[u2] = expf(-et*d2v*inv);
        }
        float zm = z[0];
        #pragma unroll
        for (int u2=1; u2<25; ++u2) zm = fmaxf(zm, z[u2]);
        float lo = zm - 1.f, hi = zm;
        for (int it=0; it<30; ++it){
            float mid = 0.5f*(lo+hi);
            float f = 0.f;
            #pragma unroll
            for (int u2=0; u2<25; ++u2) f += fmaxf(z[u2]-mid, 0.f);
            if (f >= 1.f) lo = mid; else hi = mid;
        }
        float ssum = 0.f; int kcnt = 0;
        #pragma unroll
        for (int u2=0; u2<25; ++u2){ if (z[u2] > lo){ ssum += z[u2]; kcnt++; } }
        float tau = (ssum - 1.f)/(float)kcnt;
        float as_ = 0.f;
        unsigned short* apr = att_pad + n*2560 + (s*25+vc)*32;
        #pragma unroll
        for (int u2=0; u2<25; ++u2){
            float av = atts[s*625 + u2*25 + vc] + fmaxf(z[u2]-tau, 0.f)*al;
            apr[u2] = f2bf(av);
            as_ += av;
        }
        #pragma unroll
        for (int u2=25; u2<32; ++u2) apr[u2] = 0;
        asum[n*75 + s*25 + vc] = as_;
    }
}

// ---------------- agg via MFMA (xbu u-pads masked in-register) ----------------
__global__ __launch_bounds__(256,2) void agg_mfma(const unsigned short* __restrict__ att_pad,
                                                  const unsigned short* __restrict__ xbu,
                                                  unsigned short* __restrict__ ypad){
    int bid = blockIdx.x; int n = bid >> 4; int tb = bid & 15;
    int tid = threadIdx.x; int lane = tid & 63; int w = tid >> 6;
    int lr = lane & 15, lg = lane >> 4;
    const unsigned short* ap = att_pad + n*2560;
    s16x8 a[5];
    #pragma unroll
    for (int mf=0; mf<5; ++mf) a[mf] = *(const s16x8*)&ap[(mf*16+lr)*32 + lg*8];
    int rowoff[5][4];
    #pragma unroll
    for (int mf=0; mf<5; ++mf)
        #pragma unroll
        for (int r=0; r<4; ++r){
            int m = mf*16 + lg*4 + r;
            int s = m/25, v = m - s*25;
            rowoff[mf][r] = (m < 75) ? (v*384 + s*128 + lr) : -1;
        }
    #pragma unroll
    for (int ti=0; ti<2; ++ti){
        int t = tb*8 + w*2 + ti;
        const unsigned short* bp = xbu + (size_t)n*524288 + (size_t)t*4096;
        size_t obase = ((size_t)(n*3350 + 75 + t*25))*384;
        #pragma unroll
        for (int h=0; h<2; ++h){
            s16x8 b[4];
            #pragma unroll
            for (int q=0; q<4; ++q){
                b[q] = *(const s16x8*)&bp[(h*64 + q*16 + lr)*32 + lg*8];
                if (lg == 3){
                    s16x8 t2 = b[q];
                    b[q] = (s16x8){t2[0],0,0,0,0,0,0,0};
                }
            }
            f32x4 acc[5][4];
            #pragma unroll
            for (int mf=0; mf<5; ++mf)
                #pragma unroll
                for (int q=0; q<4; ++q)
                    acc[mf][q] = (f32x4){0.f,0.f,0.f,0.f};
            #pragma unroll
            for (int mf=0; mf<5; ++mf)
                #pragma unroll
                for (int q=0; q<4; ++q)
                    acc[mf][q] = __builtin_amdgcn_mfma_f32_16x16x32_bf16(a[mf], b[q], acc[mf][q], 0, 0, 0);
            #pragma unroll
            for (int mf=0; mf<5; ++mf)
                #pragma unroll
                for (int q=0; q<4; ++q)
                    #pragma unroll
                    for (int r=0; r<4; ++r)
                        if (rowoff[mf][r] >= 0)
                            ypad[obase + rowoff[mf][r] + h*64 + q*16] = f2bf(acc[mf][q][r]);
        }
    }
}

// ---------------- fused conv+ff GEMM v9: v6 + 8-way LDS chunk swizzle (conflict-free b128 reads) ----------------
__global__ __launch_bounds__(256,3) void gemm_fused(const unsigned short* __restrict__ Amat,
                                                    const unsigned short* __restrict__ Bsrc,
                                                    const float* __restrict__ xin,
                                                    const float* __restrict__ consts,
                                                    const unsigned short* __restrict__ ffA,
                                                    const float* __restrict__ wbpart,
                                                    const float* __restrict__ asum,
                                                    float* __restrict__ outf)
{
    constexpr int NKB = 42;                   // 42 K-steps of BK=64
    __shared__ unsigned short smem[17560];    // loop: A(16KB)+B(16KB); epilogue: tile 34.8KB + asl 300B

    const int tid = threadIdx.x;
    const int bid = blockIdx.x;
    const int n   = bid/25;
    const int jn0 = (bid%25)*128;

    const int lane = tid & 63, wv = tid >> 6;
    const int wm = wv >> 1, wn = wv & 1;
    const int lr = lane & 15, lg = lane >> 4;

    unsigned short* sA = smem;
    unsigned short* sB = smem + 8192;

    // 8-way XOR chunk swizzle: row = 64 shorts = 8 chunks of 8; source chunk (cch ^ (r&7))
    // stored at linear LDS chunk cch; reads fetch LDS chunk ((kf*4+lg) ^ (lr&7)).
    auto stage = [&](int kb){
        #pragma unroll
        for (int p=0; p<4; ++p){
            int e = p*256 + tid;
            int r = e >> 3, cch = e & 7;
            int cc8 = cch ^ (r & 7);
            stage16(Amat + (size_t)r*2688 + kb*64 + cc8*8, sA + e*8);
        }
        int k32a = 2*kb, k32b = 2*kb + 1;
        int k0 = k32a % 7, s0 = (k32a/7)*32;
        int k1 = k32b % 7, s1 = (k32b/7)*32;
        const unsigned short* b0 = Bsrc + ((size_t)(n*3350 + jn0 + 25*k0))*384 + s0;
        const unsigned short* b1 = Bsrc + ((size_t)(n*3350 + jn0 + 25*k1))*384 + s1;
        #pragma unroll
        for (int p=0; p<4; ++p){
            int e = p*256 + tid;
            int r = e >> 3, cch = e & 7;
            int cc8 = cch ^ (r & 7);
            const unsigned short* src = ((cc8 >> 2) ? b1 : b0) + (size_t)r*384 + (cc8&3)*8;
            stage16(src, sB + e*8);
        }
    };

    f32x4 acc[4][4];
    #pragma unroll
    for (int a2=0;a2<4;a2++)
        #pragma unroll
        for (int b2=0;b2<4;b2++) acc[a2][b2] = (f32x4){0.f,0.f,0.f,0.f};

    for (int kb=0; kb<NKB; ++kb){
        stage(kb);
        __syncthreads();
        s16x8 a[4][2], b[4][2];
        #pragma unroll
        for (int mf=0; mf<4; ++mf)
            #pragma unroll
            for (int kf=0; kf<2; ++kf)
                a[mf][kf] = *(const s16x8*)&sA[(wm*64+mf*16+lr)*64 + (((kf*4+lg) ^ (lr&7))<<3)];
        #pragma unroll
        for (int nf=0; nf<4; ++nf)
            #pragma unroll
            for (int kf=0; kf<2; ++kf)
                b[nf][kf] = *(const s16x8*)&sB[(wn*64+nf*16+lr)*64 + (((kf*4+lg) ^ (lr&7))<<3)];
        __builtin_amdgcn_s_setprio(1);
        #pragma unroll
        for (int kf=0; kf<2; ++kf)
            #pragma unroll
            for (int mf=0; mf<4; ++mf)
                #pragma unroll
                for (int nf=0; nf<4; ++nf)
                    acc[mf][nf] = __builtin_amdgcn_mfma_f32_16x16x32_bf16(a[mf][kf], b[nf][kf], acc[mf][nf], 0, 0, 0);
        __builtin_amdgcn_s_setprio(0);
        __syncthreads();
    }

    float* asl = (float*)(smem + 17408);   // 75 floats, above the 34.8KB tile
    for (int i=tid; i<75; i+=256) asl[i] = asum[n*75 + i];
    __syncthreads();

    #pragma unroll
    for (int nf=0; nf<4; ++nf){
        int cj = wn*64 + nf*16 + lr;
        int j  = jn0 + cj;
        int t  = j/25, v = j - t*25;
        int tc = (t<3) ? t : ((t>124) ? (t-121) : 3);
        float a0 = asl[v], a1 = asl[25+v], a2 = asl[50+v];
        #pragma unroll
        for (int mf=0; mf<4; ++mf)
            #pragma unroll
            for (int r=0; r<4; ++r){
                int m = wm*64 + mf*16 + lg*4 + r;
                float b2v = wbpart[m*21+tc]*a0 + wbpart[m*21+7+tc]*a1 + wbpart[m*21+14+tc]*a2;
                float val = acc[mf][nf][r]*consts[m] + consts[128+m] + b2v
                          + xin[(size_t)n*409600 + (size_t)m*3200 + j];
                val = (val >= 0.f) ? val : 0.1f*val;
                smem[cj*136 + m] = f2bf(val);
            }
    }
    __syncthreads();

    f32x4 acc2[4][4];
    #pragma unroll
    for (int a2=0;a2<4;a2++)
        #pragma unroll
        for (int b2=0;b2<4;b2++) acc2[a2][b2] = (f32x4){0.f,0.f,0.f,0.f};
    #pragma unroll
    for (int kb2=0; kb2<4; ++kb2){
        s16x8 a2[4], b2[4];
        #pragma unroll
        for (int mf=0; mf<4; ++mf)
            a2[mf] = *(const s16x8*)&ffA[(size_t)(wm*64+mf*16+lr)*128 + kb2*32 + lg*8];
        #pragma unroll
        for (int nf=0; nf<4; ++nf)
            b2[nf] = *(const s16x8*)&smem[(wn*64+nf*16+lr)*136 + kb2*32 + lg*8];
        #pragma unroll
        for (int mf=0; mf<4; ++mf)
            #pragma unroll
            for (int nf=0; nf<4; ++nf)
                acc2[mf][nf] = __builtin_amdgcn_mfma_f32_16x16x32_bf16(a2[mf], b2[nf], acc2[mf][nf], 0, 0, 0);
    }

    #pragma unroll
    for (int mf=0; mf<4; ++mf)
        #pragma unroll
        for (int r=0; r<4; ++r){
            int co = wm*64 + mf*16 + lg*4 + r;
            float sc2 = consts[256+co], bi2 = consts[384+co];
            #pragma unroll
            for (int nf=0; nf<4; ++nf){
                int cj = wn*64 + nf*16 + lr;
                size_t idx = (size_t)n*409600 + (size_t)co*3200 + jn0 + cj;
                float val = acc2[mf][nf][r]*sc2 + bi2 + xin[idx];
                val = (val >= 0.f) ? val : 0.1f*val;
                outf[idx] = val;
            }
        }
}

extern "C" void kernel_launch(void* const* d_in, const int* in_sizes, int n_in,
                              void* d_out, int out_size, void* d_ws, size_t ws_size,
                              hipStream_t stream) {
    const float* x      = (const float*)d_in[0];
    const float* theta  = (const float*)d_in[1];
    const float* atts   = (const float*)d_in[2];
    const float* alphas = (const float*)d_in[3];
    const float* v_w    = (const float*)d_in[4];
    const float* v_b    = (const float*)d_in[5];
    const float* out_w  = (const float*)d_in[6];
    const float* out_b  = (const float*)d_in[7];
    const float* out_g  = (const float*)d_in[8];
    const float* out_be = (const float*)d_in[9];
    const float* out_m  = (const float*)d_in[10];
    const float* out_v  = (const float*)d_in[11];
    const float* ff_w   = (const float*)d_in[12];
    const float* ff_b   = (const float*)d_in[13];
    const float* ff_g   = (const float*)d_in[14];
    const float* ff_be  = (const float*)d_in[15];
    const float* ff_m   = (const float*)d_in[16];
    const float* ff_v   = (const float*)d_in[17];
    float* out = (float*)d_out;

    char* w = (char*)d_ws;
    size_t off = 0;
    auto alloc = [&](size_t b){ size_t r = off; off += (b + 1023) & ~(size_t)1023; return r; };
    float*          G      = (float*)         (w + alloc(160000));
    float*          SX     = (float*)         (w + alloc(819200));
    float*          nmaxb  = (float*)         (w + alloc(256));
    float*          asumb  = (float*)         (w + alloc(19200));
    float*          consts = (float*)         (w + alloc(2048));
    float*          wbpart = (float*)         (w + alloc(10752));
    float*          pebg   = (float*)         (w + alloc(12800));
    float*          TPgb   = (float*)         (w + alloc(2500));
    unsigned short* att_pad= (unsigned short*)(w + alloc(327680));
    unsigned short* Wr     = (unsigned short*)(w + alloc(688128));
    unsigned short* ffA    = (unsigned short*)(w + alloc(32768));
    unsigned short* xbt    = (unsigned short*)(w + alloc(52428800 + 16384));
    unsigned short* xbu    = (unsigned short*)(w + alloc(67108864));
    unsigned short* ypad   = (unsigned short*)(w + alloc(164659200));

    setup_kernel<<<9344,256,0,stream>>>(x, out_w, ff_w, v_w, v_b, out_b, out_g, out_be, out_m, out_v,
                                        ff_b, ff_g, ff_be, ff_m, ff_v,
                                        consts, ffA, ypad, wbpart, pebg, TPgb, Wr, xbt, xbu, G, SX);
    gram_part<<<512,256,0,stream>>>(xbt, G, SX);
    gram_fin<<<64,256,0,stream>>>(SX, pebg, TPgb, G, nmaxb);
    attn_kernel<<<64,128,0,stream>>>(G, nmaxb, theta, atts, alphas, att_pad, asumb);
    agg_mfma<<<1024,256,0,stream>>>(att_pad, xbu, ypad);
    gemm_fused<<<1600,256,0,stream>>>(Wr, ypad, x, consts, ffA, wbpart, asumb, out);
}